// Round 4
// baseline (1086.735 us; speedup 1.0000x reference)
//
#include <hip/hip_runtime.h>
#include <hip/hip_bf16.h>

typedef __attribute__((ext_vector_type(4))) float f32x4;
typedef __attribute__((ext_vector_type(8))) short s16x8;
typedef __attribute__((ext_vector_type(4))) short s16x4;
typedef unsigned short u16;

// ---------- helpers ----------
__device__ __forceinline__ u16 f2bf(float f) {
  union { float f; unsigned int u; } v; v.f = f;
  unsigned int r = v.u + 0x7fffu + ((v.u >> 16) & 1u);  // RNE
  return (u16)(r >> 16);
}

__device__ __forceinline__ void gload_lds16(const void* g, void* l) {
  __builtin_amdgcn_global_load_lds(
      (const __attribute__((address_space(1))) void*)g,
      (__attribute__((address_space(3))) void*)l, 16, 0, 0);
}

// ---------- elementwise f32 -> bf16 (vectorized) ----------
__global__ __launch_bounds__(256) void cvt_bf16(const float* __restrict__ in,
                                                u16* __restrict__ outp, int nquad) {
  int i = blockIdx.x * 256 + threadIdx.x;
  if (i >= nquad) return;
  f32x4 v = *(const f32x4*)(in + (size_t)i * 4);
  s16x4 o;
  o.x = (short)f2bf(v.x); o.y = (short)f2bf(v.y);
  o.z = (short)f2bf(v.z); o.w = (short)f2bf(v.w);
  *(s16x4*)(outp + (size_t)i * 4) = o;
}

// ---------- transpose + convert: in (R x C) f32 row-major -> out (C x R) bf16 ----------
__global__ __launch_bounds__(256) void transpose_cvt(const float* __restrict__ in,
                                                     u16* __restrict__ outp, int R, int C) {
  __shared__ float t[32][33];
  int c0 = blockIdx.x * 32, r0 = blockIdx.y * 32;
  int tx = threadIdx.x & 31, ty = threadIdx.x >> 5;  // 32 x 8
#pragma unroll
  for (int i = 0; i < 32; i += 8) t[ty + i][tx] = in[(size_t)(r0 + ty + i) * C + c0 + tx];
  __syncthreads();
#pragma unroll
  for (int i = 0; i < 32; i += 8)
    outp[(size_t)(c0 + ty + i) * R + r0 + tx] = f2bf(t[tx][ty + i]);
}

// ---------- RoPE table (matches the reference's interleaved-then-split layout) ----------
__global__ void rope_table(float2* __restrict__ tab) {
  int p = blockIdx.x, e = threadIdx.x;
  int j = e >> 1;
  float f1 = powf(1.0e6f, -(float)j / 64.0f);
  float f2 = powf(1.0e6f, -(float)(j + 32) / 64.0f);
  float a1 = (float)p * f1, a2 = (float)p * f2;
  float S = (e & 1) ? cosf(a1) : sinf(a1);
  float C = (e & 1) ? cosf(a2) : sinf(a2);
  tab[p * 64 + e] = make_float2(S, C);
}

// ---------- RoPE + head-pack: P (B*S x ldp) f32 -> out [b][h][s][128] bf16 ----------
__global__ __launch_bounds__(256) void rope_pack(const float* __restrict__ P,
                                                 const float2* __restrict__ tab,
                                                 u16* __restrict__ outp, int nh, int ldp,
                                                 float scale) {
  int idx = blockIdx.x * 4 + (threadIdx.x >> 6);  // over (b*nh+h)*2048+s
  int e = threadIdx.x & 63;
  int s = idx & 2047;
  int bh = idx >> 11;
  int b = bh / nh, h = bh - b * nh;
  size_t prow = ((size_t)(b * 2048 + s)) * (size_t)ldp + (size_t)h * 128;
  float x1 = P[prow + e], x2 = P[prow + e + 64];
  float2 t = tab[s * 64 + e];
  float o1 = (x1 * t.y - x2 * t.x) * scale;
  float o2 = (x2 * t.y + x1 * t.x) * scale;
  size_t orow = (size_t)idx * 128;
  outp[orow + e] = f2bf(o1);
  outp[orow + e + 64] = f2bf(o2);
}

// ---------- V pack+transpose: KVp rows (stride ldp, V at col off) -> Vt [b][kh][128][S] bf16 ----------
__global__ __launch_bounds__(256) void pack_vt(const float* __restrict__ Vp,
                                               u16* __restrict__ Vt, int ldp, int coff) {
  __shared__ float t[32][33];
  int bk = blockIdx.z;               // b*4+kh
  int b = bk >> 2, kh = bk & 3;
  int s0 = blockIdx.x * 32, d0 = blockIdx.y * 32;
  int tx = threadIdx.x & 31, ty = threadIdx.x >> 5;
  const float* in = Vp + (size_t)(b * 2048) * ldp + coff + kh * 128;
#pragma unroll
  for (int i = 0; i < 32; i += 8) t[ty + i][tx] = in[(size_t)(s0 + ty + i) * ldp + d0 + tx];
  __syncthreads();
  u16* outp = Vt + (size_t)bk * 128 * 2048;
#pragma unroll
  for (int i = 0; i < 32; i += 8)
    outp[(size_t)(d0 + ty + i) * 2048 + s0 + tx] = f2bf(t[tx][ty + i]);
}

// ---------- GEMM: C (MxN f32) = A (MxK bf16) * BT (NxK bf16)^T ; 128x128 tile ----------
__global__ __launch_bounds__(256) void gemm_bt(const u16* __restrict__ A,
                                               const u16* __restrict__ BT,
                                               float* __restrict__ C, int M, int N, int K) {
  __shared__ u16 lA[128 * 32];
  __shared__ u16 lB[128 * 32];
  const int tid = threadIdx.x;
  const int lane = tid & 63, wave = tid >> 6;
  const int bm = blockIdx.y * 128, bn = blockIdx.x * 128;
  const int wr = (wave >> 1) * 64, wc = (wave & 1) * 64;
  const int r = lane & 15, g = lane >> 4;

  f32x4 acc[4][4];
#pragma unroll
  for (int i = 0; i < 4; i++)
#pragma unroll
    for (int j = 0; j < 4; j++) acc[i][j] = (f32x4){0.f, 0.f, 0.f, 0.f};

  const int o0 = wave * 2048 + lane * 16;
  const int row0 = o0 >> 6, cb0 = (o0 & 63) >> 1;
  const int o1 = o0 + 1024;
  const int row1 = o1 >> 6, cb1 = (o1 & 63) >> 1;
  const u16* a0 = A + (size_t)(bm + row0) * K + cb0;
  const u16* a1 = A + (size_t)(bm + row1) * K + cb1;
  const u16* b0 = BT + (size_t)(bn + row0) * K + cb0;
  const u16* b1 = BT + (size_t)(bn + row1) * K + cb1;
  u16* lA0 = lA + wave * 2 * 512; u16* lA1 = lA + (wave * 2 + 1) * 512;
  u16* lB0 = lB + wave * 2 * 512; u16* lB1 = lB + (wave * 2 + 1) * 512;

  for (int kt = 0; kt < K; kt += 32) {
    __syncthreads();
    gload_lds16(a0 + kt, lA0);
    gload_lds16(a1 + kt, lA1);
    gload_lds16(b0 + kt, lB0);
    gload_lds16(b1 + kt, lB1);
    __syncthreads();
    s16x8 af[4], bf[4];
#pragma unroll
    for (int m2 = 0; m2 < 4; m2++) af[m2] = *(const s16x8*)(lA + (wr + m2 * 16 + r) * 32 + g * 8);
#pragma unroll
    for (int n2 = 0; n2 < 4; n2++) bf[n2] = *(const s16x8*)(lB + (wc + n2 * 16 + r) * 32 + g * 8);
#pragma unroll
    for (int m2 = 0; m2 < 4; m2++)
#pragma unroll
      for (int n2 = 0; n2 < 4; n2++)
        acc[m2][n2] = __builtin_amdgcn_mfma_f32_16x16x32_bf16(af[m2], bf[n2], acc[m2][n2], 0, 0, 0);
  }
#pragma unroll
  for (int m2 = 0; m2 < 4; m2++)
#pragma unroll
    for (int n2 = 0; n2 < 4; n2++)
#pragma unroll
      for (int jj = 0; jj < 4; jj++)
        C[(size_t)(bm + wr + m2 * 16 + g * 4 + jj) * N + (bn + wc + n2 * 16 + r)] =
            acc[m2][n2][jj];
}

// ---------- causal GQA flash attention, 8-wave blocks (QBLK=128), LDS-staged K/V ----------
// Q [b][28][S][128] bf16 (pre-scaled), K [b][4][S][128] bf16, Vt [b][4][128][S] bf16
// AO (B*S x 3584) bf16.  Wave w owns rows qt*128+16w..+15. KVBLK=32.
__global__ __launch_bounds__(512, 8) void attn_kernel(const u16* __restrict__ Q,
                                                      const u16* __restrict__ K,
                                                      const u16* __restrict__ Vt,
                                                      u16* __restrict__ AO) {
  constexpr int S = 2048, NH = 28, NKV = 4, D = 128;
  __shared__ u16 Kl[2][32 * 128];  // [row][256B], stored byte ^= (row&7)<<4
  __shared__ u16 Vl[2][32 * 128];  // [d][64B],   stored byte ^= ((d>>1)&7)<<4
  const int tid = threadIdx.x;
  const int lane = tid & 63, w = tid >> 6;
  const int r = lane & 15, g = lane >> 4;
  const int qt = (int)gridDim.x - 1 - (int)blockIdx.x;  // heavy tiles first
  const int h = blockIdx.y, b = blockIdx.z;
  const int q0 = qt * 128 + w * 16;
  const int kh = h & 3;
  const u16* Qb = Q + ((size_t)(b * NH + h) * S + q0) * D;
  const u16* Kb = K + ((size_t)(b * NKV + kh) * S) * D;
  const u16* Vb = Vt + ((size_t)(b * NKV + kh) * D) * S;

  s16x8 qf[4];
#pragma unroll
  for (int kb = 0; kb < 4; kb++)
    qf[kb] = *(const s16x8*)(Qb + (size_t)r * D + kb * 32 + g * 8);

  // staging: 512 threads x 16B = 8KB tile each for K and V.
  // LDS dest linear at byte o = tid*16; global source pre-swizzled (involutions).
  const int o = tid * 16;
  const int krow = o >> 8;
  const int kcol = ((o & 255) ^ ((krow & 7) << 4)) >> 1;
  const u16* sK = Kb + (size_t)krow * D + kcol;
  const int p = o ^ (((o >> 7) & 7) << 4);
  const u16* sV = Vb + (size_t)(p >> 6) * S + ((p & 63) >> 1);

  f32x4 o8[8];
#pragma unroll
  for (int c = 0; c < 8; c++) o8[c] = (f32x4){0.f, 0.f, 0.f, 0.f};
  float m = -1e30f, lsum = 0.f;
  const int qg = q0 + r;
  const int NT = 4 * qt + 4;

  // prologue stage
  gload_lds16(sK, (u16*)Kl[0] + tid * 8);
  gload_lds16(sV, (u16*)Vl[0] + tid * 8);
  __syncthreads();

  int cur = 0;
  for (int t = 0; t < NT; ++t) {
    const int j = t * 32;
    if (t + 1 < NT) {
      const int jn = j + 32;
      gload_lds16(sK + (size_t)jn * D, (u16*)Kl[cur ^ 1] + tid * 8);
      gload_lds16(sV + jn, (u16*)Vl[cur ^ 1] + tid * 8);
    }
    if (j <= q0 + 15) {  // wave-uniform active check
      // ---- QK^T (swapped): lane holds P[kv=16*hi+g*4+jj][q=r] ----
      f32x4 st0 = (f32x4){0.f, 0.f, 0.f, 0.f};
      f32x4 st1 = (f32x4){0.f, 0.f, 0.f, 0.f};
      const int swz = (r & 7) << 4;
      const char* Kc = (const char*)Kl[cur];
      __builtin_amdgcn_s_setprio(1);
#pragma unroll
      for (int kb = 0; kb < 4; kb++) {
        int cb = (kb * 64 + g * 16) ^ swz;
        s16x8 kf = *(const s16x8*)(Kc + r * 256 + cb);
        st0 = __builtin_amdgcn_mfma_f32_16x16x32_bf16(kf, qf[kb], st0, 0, 0, 0);
      }
#pragma unroll
      for (int kb = 0; kb < 4; kb++) {
        int cb = (kb * 64 + g * 16) ^ swz;
        s16x8 kf = *(const s16x8*)(Kc + (r + 16) * 256 + cb);
        st1 = __builtin_amdgcn_mfma_f32_16x16x32_bf16(kf, qf[kb], st1, 0, 0, 0);
      }
      __builtin_amdgcn_s_setprio(0);
      float s8v[8];
      if (j + 31 <= q0) {  // fully unmasked tile
#pragma unroll
        for (int jj = 0; jj < 4; jj++) { s8v[jj] = st0[jj]; s8v[jj + 4] = st1[jj]; }
      } else {
#pragma unroll
        for (int jj = 0; jj < 4; jj++) {
          int kv0 = j + g * 4 + jj;
          s8v[jj] = (kv0 > qg) ? -1e30f : st0[jj];
          s8v[jj + 4] = (kv0 + 16 > qg) ? -1e30f : st1[jj];
        }
      }
      // ---- online softmax (row = q = r, reduce over g-lanes) ----
      float pm = fmaxf(fmaxf(fmaxf(s8v[0], s8v[1]), fmaxf(s8v[2], s8v[3])),
                       fmaxf(fmaxf(s8v[4], s8v[5]), fmaxf(s8v[6], s8v[7])));
      pm = fmaxf(pm, __shfl_xor(pm, 16));
      pm = fmaxf(pm, __shfl_xor(pm, 32));
      // defer-max (T13): skip rescale when max growth <= 8 across the wave
      const bool defer = __all(pm <= m + 8.f);
      float mnew, fr;
      if (defer) { mnew = m; fr = 1.f; }
      else { mnew = fmaxf(m, pm); fr = __expf(m - mnew); }
      float pv[8], psum = 0.f;
#pragma unroll
      for (int i2 = 0; i2 < 8; i2++) { pv[i2] = __expf(s8v[i2] - mnew); psum += pv[i2]; }
      psum += __shfl_xor(psum, 16);
      psum += __shfl_xor(psum, 32);
      lsum = lsum * fr + psum;
      m = mnew;
      // ---- P -> bf16 ----
      // lane (r,g) holds pk[2*hi+p] = P[q=r][kvl=16*hi+4g+2p .. +1]
      unsigned pk[4];
#pragma unroll
      for (int i2 = 0; i2 < 4; i2++) {
        __hip_bfloat162 hv = __float22bfloat162_rn(make_float2(pv[2 * i2], pv[2 * i2 + 1]));
        union { __hip_bfloat162 h; unsigned u; } cv; cv.h = hv; pk[i2] = cv.u;
      }
      // ---- redistribute to A-fragment layout: dest (r,g) slot d needs
      //      pk[2*(g>>1)+(d&1)] from lane r + 32*(g&1) + 16*(d>>1). ----
      int L0 = r + ((g & 1) << 5);
      unsigned a0 = (unsigned)__shfl((int)pk[0], L0);
      unsigned a1 = (unsigned)__shfl((int)pk[1], L0);
      unsigned a2 = (unsigned)__shfl((int)pk[2], L0);
      unsigned a3 = (unsigned)__shfl((int)pk[3], L0);
      unsigned b0 = (unsigned)__shfl((int)pk[0], L0 + 16);
      unsigned b1 = (unsigned)__shfl((int)pk[1], L0 + 16);
      unsigned b2 = (unsigned)__shfl((int)pk[2], L0 + 16);
      unsigned b3 = (unsigned)__shfl((int)pk[3], L0 + 16);
      union { unsigned u[4]; s16x8 v; } pu;
      pu.u[0] = (g < 2) ? a0 : a2;
      pu.u[1] = (g < 2) ? a1 : a3;
      pu.u[2] = (g < 2) ? b0 : b2;
      pu.u[3] = (g < 2) ? b1 : b3;
      s16x8 pa = pu.v;
      float fB[4];
      if (!defer) {
#pragma unroll
        for (int jj = 0; jj < 4; jj++) fB[jj] = __shfl(fr, g * 4 + jj);
      }
      // ---- PV ----
      const char* Vc = (const char*)Vl[cur];
      __builtin_amdgcn_s_setprio(1);
#pragma unroll
      for (int c = 0; c < 8; c++) {
        int pbyte = (c * 16 + r) * 64 + g * 16;
        int vaddr = pbyte ^ ((r >> 1) << 4);
        s16x8 vf = *(const s16x8*)(Vc + vaddr);
        f32x4 oc = o8[c];
        if (!defer) { oc.x *= fB[0]; oc.y *= fB[1]; oc.z *= fB[2]; oc.w *= fB[3]; }
        o8[c] = __builtin_amdgcn_mfma_f32_16x16x32_bf16(pa, vf, oc, 0, 0, 0);
      }
      __builtin_amdgcn_s_setprio(0);
    }
    __syncthreads();
    cur ^= 1;
  }

  float lB[4];
#pragma unroll
  for (int jj = 0; jj < 4; jj++) lB[jj] = __shfl(lsum, g * 4 + jj);
#pragma unroll
  for (int c = 0; c < 8; c++)
#pragma unroll
    for (int jj = 0; jj < 4; jj++) {
      float val = o8[c][jj] / lB[jj];
      AO[(size_t)(b * S + q0 + g * 4 + jj) * 3584 + h * 128 + c * 16 + r] = f2bf(val);
    }
}

// ---------- workspace layout (bytes) ----------
static const size_t OFF_XBF = 0;            // 4096x3584 bf16
static const size_t OFF_WQT = 29360128;     // 3584x3584 bf16
static const size_t OFF_WKT = 55050240;     // 512x3584 bf16   (contiguous with WVT ->
static const size_t OFF_WVT = 58720256;     // 512x3584 bf16    combined [1024][3584])
static const size_t OFF_WOT = 62390272;     // 3584x3584 bf16
static const size_t OFF_TAB = 88080384;     // 2048x64 float2
static const size_t OFF_QBF = 89128960;     // [2][28][2048][128] bf16
static const size_t OFF_KBF = 118489088;    // [2][4][2048][128] bf16
static const size_t OFF_VT  = 122683392;    // [2][4][128][2048] bf16
static const size_t OFF_QP  = 126877696;    // 4096x3584 f32 (reused: AO bf16)
static const size_t OFF_KVP = 185597952;    // 4096x1024 f32
// total: 202375168 bytes

extern "C" void kernel_launch(void* const* d_in, const int* in_sizes, int n_in,
                              void* d_out, int out_size, void* d_ws, size_t ws_size,
                              hipStream_t stream) {
  const float* X  = (const float*)d_in[0];
  const float* Wq = (const float*)d_in[1];
  const float* Wk = (const float*)d_in[2];
  const float* Wv = (const float*)d_in[3];
  const float* Wo = (const float*)d_in[4];
  float* out = (float*)d_out;
  char* ws = (char*)d_ws;

  u16* Xbf = (u16*)(ws + OFF_XBF);
  u16* WqT = (u16*)(ws + OFF_WQT);
  u16* WkT = (u16*)(ws + OFF_WKT);
  u16* WvT = (u16*)(ws + OFF_WVT);
  u16* WoT = (u16*)(ws + OFF_WOT);
  float2* tab = (float2*)(ws + OFF_TAB);
  u16* Qbf = (u16*)(ws + OFF_QBF);
  u16* Kbf = (u16*)(ws + OFF_KBF);
  u16* Vtb = (u16*)(ws + OFF_VT);
  float* Qp = (float*)(ws + OFF_QP);
  float* KVp = (float*)(ws + OFF_KVP);
  u16* AO  = (u16*)(ws + OFF_QP);  // reuse Qp region after rope_pack

  // conversions
  cvt_bf16<<<14336, 256, 0, stream>>>(X, Xbf, 3670016);
  transpose_cvt<<<dim3(112, 112), 256, 0, stream>>>(Wq, WqT, 3584, 3584);
  transpose_cvt<<<dim3(16, 112), 256, 0, stream>>>(Wk, WkT, 3584, 512);
  transpose_cvt<<<dim3(16, 112), 256, 0, stream>>>(Wv, WvT, 3584, 512);
  transpose_cvt<<<dim3(112, 112), 256, 0, stream>>>(Wo, WoT, 3584, 3584);
  rope_table<<<2048, 64, 0, stream>>>(tab);

  // projections (K and V fused: BT = [WkT ; WvT] is contiguous, N=1024)
  gemm_bt<<<dim3(28, 32), 256, 0, stream>>>(Xbf, WqT, Qp, 4096, 3584, 3584);
  gemm_bt<<<dim3(8, 32), 256, 0, stream>>>(Xbf, WkT, KVp, 4096, 1024, 3584);

  // rope + pack (scale folded into Q)
  rope_pack<<<28672, 256, 0, stream>>>(Qp, tab, Qbf, 28, 3584, 0.08838834764831845f);
  rope_pack<<<4096, 256, 0, stream>>>(KVp, tab, Kbf, 4, 1024, 1.0f);
  pack_vt<<<dim3(64, 4, 8), 256, 0, stream>>>(KVp, Vtb, 1024, 512);

  // attention
  attn_kernel<<<dim3(16, 28, 2), 512, 0, stream>>>(Qbf, Kbf, Vtb, AO);

  // output projection
  gemm_bt<<<dim3(28, 32), 256, 0, stream>>>(AO, WoT, out, 4096, 3584, 3584);
}

// Round 5
// 740.625 us; speedup vs baseline: 1.4673x; 1.4673x over previous
//
#include <hip/hip_runtime.h>
#include <hip/hip_bf16.h>

typedef __attribute__((ext_vector_type(4))) float f32x4;
typedef __attribute__((ext_vector_type(8))) short s16x8;
typedef __attribute__((ext_vector_type(4))) short s16x4;
typedef unsigned short u16;

// ---------- helpers ----------
__device__ __forceinline__ u16 f2bf(float f) {
  union { float f; unsigned int u; } v; v.f = f;
  unsigned int r = v.u + 0x7fffu + ((v.u >> 16) & 1u);  // RNE
  return (u16)(r >> 16);
}

__device__ __forceinline__ void gload_lds16(const void* g, void* l) {
  __builtin_amdgcn_global_load_lds(
      (const __attribute__((address_space(1))) void*)g,
      (__attribute__((address_space(3))) void*)l, 16, 0, 0);
}

// ---------- elementwise f32 -> bf16 (vectorized) ----------
__global__ __launch_bounds__(256) void cvt_bf16(const float* __restrict__ in,
                                                u16* __restrict__ outp, int nquad) {
  int i = blockIdx.x * 256 + threadIdx.x;
  if (i >= nquad) return;
  f32x4 v = *(const f32x4*)(in + (size_t)i * 4);
  s16x4 o;
  o.x = (short)f2bf(v.x); o.y = (short)f2bf(v.y);
  o.z = (short)f2bf(v.z); o.w = (short)f2bf(v.w);
  *(s16x4*)(outp + (size_t)i * 4) = o;
}

// ---------- transpose + convert: in (R x C) f32 row-major -> out (C x R) bf16 ----------
__global__ __launch_bounds__(256) void transpose_cvt(const float* __restrict__ in,
                                                     u16* __restrict__ outp, int R, int C) {
  __shared__ float t[32][33];
  int c0 = blockIdx.x * 32, r0 = blockIdx.y * 32;
  int tx = threadIdx.x & 31, ty = threadIdx.x >> 5;  // 32 x 8
#pragma unroll
  for (int i = 0; i < 32; i += 8) t[ty + i][tx] = in[(size_t)(r0 + ty + i) * C + c0 + tx];
  __syncthreads();
#pragma unroll
  for (int i = 0; i < 32; i += 8)
    outp[(size_t)(c0 + ty + i) * R + r0 + tx] = f2bf(t[tx][ty + i]);
}

// ---------- RoPE table (matches the reference's interleaved-then-split layout) ----------
__global__ void rope_table(float2* __restrict__ tab) {
  int p = blockIdx.x, e = threadIdx.x;
  int j = e >> 1;
  float f1 = powf(1.0e6f, -(float)j / 64.0f);
  float f2 = powf(1.0e6f, -(float)(j + 32) / 64.0f);
  float a1 = (float)p * f1, a2 = (float)p * f2;
  float S = (e & 1) ? cosf(a1) : sinf(a1);
  float C = (e & 1) ? cosf(a2) : sinf(a2);
  tab[p * 64 + e] = make_float2(S, C);
}

// ---------- RoPE + head-pack: P (B*S x ldp) f32 -> out [b][h][s][128] bf16 ----------
__global__ __launch_bounds__(256) void rope_pack(const float* __restrict__ P,
                                                 const float2* __restrict__ tab,
                                                 u16* __restrict__ outp, int nh, int ldp,
                                                 float scale) {
  int idx = blockIdx.x * 4 + (threadIdx.x >> 6);  // over (b*nh+h)*2048+s
  int e = threadIdx.x & 63;
  int s = idx & 2047;
  int bh = idx >> 11;
  int b = bh / nh, h = bh - b * nh;
  size_t prow = ((size_t)(b * 2048 + s)) * (size_t)ldp + (size_t)h * 128;
  float x1 = P[prow + e], x2 = P[prow + e + 64];
  float2 t = tab[s * 64 + e];
  float o1 = (x1 * t.y - x2 * t.x) * scale;
  float o2 = (x2 * t.y + x1 * t.x) * scale;
  size_t orow = (size_t)idx * 128;
  outp[orow + e] = f2bf(o1);
  outp[orow + e + 64] = f2bf(o2);
}

// ---------- V pack+transpose: KVp rows (stride ldp, V at col off) -> Vt [b][kh][128][S] bf16 ----------
__global__ __launch_bounds__(256) void pack_vt(const float* __restrict__ Vp,
                                               u16* __restrict__ Vt, int ldp, int coff) {
  __shared__ float t[32][33];
  int bk = blockIdx.z;               // b*4+kh
  int b = bk >> 2, kh = bk & 3;
  int s0 = blockIdx.x * 32, d0 = blockIdx.y * 32;
  int tx = threadIdx.x & 31, ty = threadIdx.x >> 5;
  const float* in = Vp + (size_t)(b * 2048) * ldp + coff + kh * 128;
#pragma unroll
  for (int i = 0; i < 32; i += 8) t[ty + i][tx] = in[(size_t)(s0 + ty + i) * ldp + d0 + tx];
  __syncthreads();
  u16* outp = Vt + (size_t)bk * 128 * 2048;
#pragma unroll
  for (int i = 0; i < 32; i += 8)
    outp[(size_t)(d0 + ty + i) * 2048 + s0 + tx] = f2bf(t[tx][ty + i]);
}

// ---------- GEMM: C (MxN f32) = A (MxK bf16) * BT (NxK bf16)^T ; 128x128 tile ----------
__global__ __launch_bounds__(256) void gemm_bt(const u16* __restrict__ A,
                                               const u16* __restrict__ BT,
                                               float* __restrict__ C, int M, int N, int K) {
  __shared__ u16 lA[128 * 32];
  __shared__ u16 lB[128 * 32];
  const int tid = threadIdx.x;
  const int lane = tid & 63, wave = tid >> 6;
  const int bm = blockIdx.y * 128, bn = blockIdx.x * 128;
  const int wr = (wave >> 1) * 64, wc = (wave & 1) * 64;
  const int r = lane & 15, g = lane >> 4;

  f32x4 acc[4][4];
#pragma unroll
  for (int i = 0; i < 4; i++)
#pragma unroll
    for (int j = 0; j < 4; j++) acc[i][j] = (f32x4){0.f, 0.f, 0.f, 0.f};

  const int o0 = wave * 2048 + lane * 16;
  const int row0 = o0 >> 6, cb0 = (o0 & 63) >> 1;
  const int o1 = o0 + 1024;
  const int row1 = o1 >> 6, cb1 = (o1 & 63) >> 1;
  const u16* a0 = A + (size_t)(bm + row0) * K + cb0;
  const u16* a1 = A + (size_t)(bm + row1) * K + cb1;
  const u16* b0 = BT + (size_t)(bn + row0) * K + cb0;
  const u16* b1 = BT + (size_t)(bn + row1) * K + cb1;
  u16* lA0 = lA + wave * 2 * 512; u16* lA1 = lA + (wave * 2 + 1) * 512;
  u16* lB0 = lB + wave * 2 * 512; u16* lB1 = lB + (wave * 2 + 1) * 512;

  for (int kt = 0; kt < K; kt += 32) {
    __syncthreads();
    gload_lds16(a0 + kt, lA0);
    gload_lds16(a1 + kt, lA1);
    gload_lds16(b0 + kt, lB0);
    gload_lds16(b1 + kt, lB1);
    __syncthreads();
    s16x8 af[4], bf[4];
#pragma unroll
    for (int m2 = 0; m2 < 4; m2++) af[m2] = *(const s16x8*)(lA + (wr + m2 * 16 + r) * 32 + g * 8);
#pragma unroll
    for (int n2 = 0; n2 < 4; n2++) bf[n2] = *(const s16x8*)(lB + (wc + n2 * 16 + r) * 32 + g * 8);
#pragma unroll
    for (int m2 = 0; m2 < 4; m2++)
#pragma unroll
      for (int n2 = 0; n2 < 4; n2++)
        acc[m2][n2] = __builtin_amdgcn_mfma_f32_16x16x32_bf16(af[m2], bf[n2], acc[m2][n2], 0, 0, 0);
  }
#pragma unroll
  for (int m2 = 0; m2 < 4; m2++)
#pragma unroll
    for (int n2 = 0; n2 < 4; n2++)
#pragma unroll
      for (int jj = 0; jj < 4; jj++)
        C[(size_t)(bm + wr + m2 * 16 + g * 4 + jj) * N + (bn + wc + n2 * 16 + r)] =
            acc[m2][n2][jj];
}

// ---------- causal GQA flash attention, 8-wave blocks (QBLK=128), LDS-staged K/V ----------
// Q [b][28][S][128] bf16 (pre-scaled), K [b][4][S][128] bf16, Vt [b][4][128][S] bf16
// AO (B*S x 3584) bf16.  Wave w owns rows qt*128+16w..+15. KVBLK=32.
// NOTE: min-waves/EU=4 (VGPR cap 128). Forcing 8 caused 32-VGPR spill config
// (round 4: +1.2GB scratch traffic, 612us). Compiler lands ~60-70 VGPR.
__global__ __launch_bounds__(512, 4) void attn_kernel(const u16* __restrict__ Q,
                                                      const u16* __restrict__ K,
                                                      const u16* __restrict__ Vt,
                                                      u16* __restrict__ AO) {
  constexpr int S = 2048, NH = 28, NKV = 4, D = 128;
  __shared__ u16 Kl[2][32 * 128];  // [row][256B], stored byte ^= (row&7)<<4
  __shared__ u16 Vl[2][32 * 128];  // [d][64B],   stored byte ^= ((d>>1)&7)<<4
  const int tid = threadIdx.x;
  const int lane = tid & 63, w = tid >> 6;
  const int r = lane & 15, g = lane >> 4;
  const int qt = (int)gridDim.x - 1 - (int)blockIdx.x;  // heavy tiles first
  const int h = blockIdx.y, b = blockIdx.z;
  const int q0 = qt * 128 + w * 16;
  const int kh = h & 3;
  const u16* Qb = Q + ((size_t)(b * NH + h) * S + q0) * D;
  const u16* Kb = K + ((size_t)(b * NKV + kh) * S) * D;
  const u16* Vb = Vt + ((size_t)(b * NKV + kh) * D) * S;

  s16x8 qf[4];
#pragma unroll
  for (int kb = 0; kb < 4; kb++)
    qf[kb] = *(const s16x8*)(Qb + (size_t)r * D + kb * 32 + g * 8);

  // staging: 512 threads x 16B = 8KB tile each for K and V.
  // LDS dest linear at byte o = tid*16; global source pre-swizzled (involutions).
  const int o = tid * 16;
  const int krow = o >> 8;
  const int kcol = ((o & 255) ^ ((krow & 7) << 4)) >> 1;
  const u16* sK = Kb + (size_t)krow * D + kcol;
  const int p = o ^ (((o >> 7) & 7) << 4);
  const u16* sV = Vb + (size_t)(p >> 6) * S + ((p & 63) >> 1);

  f32x4 o8[8];
#pragma unroll
  for (int c = 0; c < 8; c++) o8[c] = (f32x4){0.f, 0.f, 0.f, 0.f};
  float m = -1e30f, lsum = 0.f;
  const int qg = q0 + r;
  const int NT = 4 * qt + 4;

  // prologue stage
  gload_lds16(sK, (u16*)Kl[0] + tid * 8);
  gload_lds16(sV, (u16*)Vl[0] + tid * 8);
  __syncthreads();

  int cur = 0;
  for (int t = 0; t < NT; ++t) {
    const int j = t * 32;
    if (t + 1 < NT) {
      const int jn = j + 32;
      gload_lds16(sK + (size_t)jn * D, (u16*)Kl[cur ^ 1] + tid * 8);
      gload_lds16(sV + jn, (u16*)Vl[cur ^ 1] + tid * 8);
    }
    if (j <= q0 + 15) {  // wave-uniform active check
      // ---- QK^T (swapped): lane holds P[kv=16*hi+g*4+jj][q=r] ----
      f32x4 st0 = (f32x4){0.f, 0.f, 0.f, 0.f};
      f32x4 st1 = (f32x4){0.f, 0.f, 0.f, 0.f};
      const int swz = (r & 7) << 4;
      const char* Kc = (const char*)Kl[cur];
      __builtin_amdgcn_s_setprio(1);
#pragma unroll
      for (int kb = 0; kb < 4; kb++) {
        int cb = (kb * 64 + g * 16) ^ swz;
        s16x8 kf = *(const s16x8*)(Kc + r * 256 + cb);
        st0 = __builtin_amdgcn_mfma_f32_16x16x32_bf16(kf, qf[kb], st0, 0, 0, 0);
      }
#pragma unroll
      for (int kb = 0; kb < 4; kb++) {
        int cb = (kb * 64 + g * 16) ^ swz;
        s16x8 kf = *(const s16x8*)(Kc + (r + 16) * 256 + cb);
        st1 = __builtin_amdgcn_mfma_f32_16x16x32_bf16(kf, qf[kb], st1, 0, 0, 0);
      }
      __builtin_amdgcn_s_setprio(0);
      float s8v[8];
      if (j + 31 <= q0) {  // fully unmasked tile
#pragma unroll
        for (int jj = 0; jj < 4; jj++) { s8v[jj] = st0[jj]; s8v[jj + 4] = st1[jj]; }
      } else {
#pragma unroll
        for (int jj = 0; jj < 4; jj++) {
          int kv0 = j + g * 4 + jj;
          s8v[jj] = (kv0 > qg) ? -1e30f : st0[jj];
          s8v[jj + 4] = (kv0 + 16 > qg) ? -1e30f : st1[jj];
        }
      }
      // ---- online softmax (row = q = r, reduce over g-lanes) ----
      float pm = fmaxf(fmaxf(fmaxf(s8v[0], s8v[1]), fmaxf(s8v[2], s8v[3])),
                       fmaxf(fmaxf(s8v[4], s8v[5]), fmaxf(s8v[6], s8v[7])));
      pm = fmaxf(pm, __shfl_xor(pm, 16));
      pm = fmaxf(pm, __shfl_xor(pm, 32));
      // defer-max (T13): skip rescale when max growth <= 8 across the wave
      const bool defer = __all(pm <= m + 8.f);
      float mnew, fr;
      if (defer) { mnew = m; fr = 1.f; }
      else { mnew = fmaxf(m, pm); fr = __expf(m - mnew); }
      float pv[8], psum = 0.f;
#pragma unroll
      for (int i2 = 0; i2 < 8; i2++) { pv[i2] = __expf(s8v[i2] - mnew); psum += pv[i2]; }
      psum += __shfl_xor(psum, 16);
      psum += __shfl_xor(psum, 32);
      lsum = lsum * fr + psum;
      m = mnew;
      // ---- P -> bf16 ----
      // lane (r,g) holds pk[2*hi+p] = P[q=r][kvl=16*hi+4g+2p .. +1]
      unsigned pk[4];
#pragma unroll
      for (int i2 = 0; i2 < 4; i2++) {
        __hip_bfloat162 hv = __float22bfloat162_rn(make_float2(pv[2 * i2], pv[2 * i2 + 1]));
        union { __hip_bfloat162 h; unsigned u; } cv; cv.h = hv; pk[i2] = cv.u;
      }
      // ---- redistribute to A-fragment layout: dest (r,g) slot d needs
      //      pk[2*(g>>1)+(d&1)] from lane r + 32*(g&1) + 16*(d>>1). ----
      int L0 = r + ((g & 1) << 5);
      unsigned a0 = (unsigned)__shfl((int)pk[0], L0);
      unsigned a1 = (unsigned)__shfl((int)pk[1], L0);
      unsigned a2 = (unsigned)__shfl((int)pk[2], L0);
      unsigned a3 = (unsigned)__shfl((int)pk[3], L0);
      unsigned b0 = (unsigned)__shfl((int)pk[0], L0 + 16);
      unsigned b1 = (unsigned)__shfl((int)pk[1], L0 + 16);
      unsigned b2 = (unsigned)__shfl((int)pk[2], L0 + 16);
      unsigned b3 = (unsigned)__shfl((int)pk[3], L0 + 16);
      union { unsigned u[4]; s16x8 v; } pu;
      pu.u[0] = (g < 2) ? a0 : a2;
      pu.u[1] = (g < 2) ? a1 : a3;
      pu.u[2] = (g < 2) ? b0 : b2;
      pu.u[3] = (g < 2) ? b1 : b3;
      s16x8 pa = pu.v;
      float fB[4];
      if (!defer) {
#pragma unroll
        for (int jj = 0; jj < 4; jj++) fB[jj] = __shfl(fr, g * 4 + jj);
      }
      // ---- PV ----
      const char* Vc = (const char*)Vl[cur];
      __builtin_amdgcn_s_setprio(1);
#pragma unroll
      for (int c = 0; c < 8; c++) {
        int pbyte = (c * 16 + r) * 64 + g * 16;
        int vaddr = pbyte ^ ((r >> 1) << 4);
        s16x8 vf = *(const s16x8*)(Vc + vaddr);
        f32x4 oc = o8[c];
        if (!defer) { oc.x *= fB[0]; oc.y *= fB[1]; oc.z *= fB[2]; oc.w *= fB[3]; }
        o8[c] = __builtin_amdgcn_mfma_f32_16x16x32_bf16(pa, vf, oc, 0, 0, 0);
      }
      __builtin_amdgcn_s_setprio(0);
    }
    __syncthreads();
    cur ^= 1;
  }

  float lB[4];
#pragma unroll
  for (int jj = 0; jj < 4; jj++) lB[jj] = __shfl(lsum, g * 4 + jj);
#pragma unroll
  for (int c = 0; c < 8; c++)
#pragma unroll
    for (int jj = 0; jj < 4; jj++) {
      float val = o8[c][jj] / lB[jj];
      AO[(size_t)(b * S + q0 + g * 4 + jj) * 3584 + h * 128 + c * 16 + r] = f2bf(val);
    }
}

// ---------- workspace layout (bytes) ----------
static const size_t OFF_XBF = 0;            // 4096x3584 bf16
static const size_t OFF_WQT = 29360128;     // 3584x3584 bf16
static const size_t OFF_WKT = 55050240;     // 512x3584 bf16   (contiguous with WVT ->
static const size_t OFF_WVT = 58720256;     // 512x3584 bf16    combined [1024][3584])
static const size_t OFF_WOT = 62390272;     // 3584x3584 bf16
static const size_t OFF_TAB = 88080384;     // 2048x64 float2
static const size_t OFF_QBF = 89128960;     // [2][28][2048][128] bf16
static const size_t OFF_KBF = 118489088;    // [2][4][2048][128] bf16
static const size_t OFF_VT  = 122683392;    // [2][4][128][2048] bf16
static const size_t OFF_QP  = 126877696;    // 4096x3584 f32 (reused: AO bf16)
static const size_t OFF_KVP = 185597952;    // 4096x1024 f32
// total: 202375168 bytes

extern "C" void kernel_launch(void* const* d_in, const int* in_sizes, int n_in,
                              void* d_out, int out_size, void* d_ws, size_t ws_size,
                              hipStream_t stream) {
  const float* X  = (const float*)d_in[0];
  const float* Wq = (const float*)d_in[1];
  const float* Wk = (const float*)d_in[2];
  const float* Wv = (const float*)d_in[3];
  const float* Wo = (const float*)d_in[4];
  float* out = (float*)d_out;
  char* ws = (char*)d_ws;

  u16* Xbf = (u16*)(ws + OFF_XBF);
  u16* WqT = (u16*)(ws + OFF_WQT);
  u16* WkT = (u16*)(ws + OFF_WKT);
  u16* WvT = (u16*)(ws + OFF_WVT);
  u16* WoT = (u16*)(ws + OFF_WOT);
  float2* tab = (float2*)(ws + OFF_TAB);
  u16* Qbf = (u16*)(ws + OFF_QBF);
  u16* Kbf = (u16*)(ws + OFF_KBF);
  u16* Vtb = (u16*)(ws + OFF_VT);
  float* Qp = (float*)(ws + OFF_QP);
  float* KVp = (float*)(ws + OFF_KVP);
  u16* AO  = (u16*)(ws + OFF_QP);  // reuse Qp region after rope_pack

  // conversions
  cvt_bf16<<<14336, 256, 0, stream>>>(X, Xbf, 3670016);
  transpose_cvt<<<dim3(112, 112), 256, 0, stream>>>(Wq, WqT, 3584, 3584);
  transpose_cvt<<<dim3(16, 112), 256, 0, stream>>>(Wk, WkT, 3584, 512);
  transpose_cvt<<<dim3(16, 112), 256, 0, stream>>>(Wv, WvT, 3584, 512);
  transpose_cvt<<<dim3(112, 112), 256, 0, stream>>>(Wo, WoT, 3584, 3584);
  rope_table<<<2048, 64, 0, stream>>>(tab);

  // projections (K and V fused: BT = [WkT ; WvT] is contiguous, N=1024)
  gemm_bt<<<dim3(28, 32), 256, 0, stream>>>(Xbf, WqT, Qp, 4096, 3584, 3584);
  gemm_bt<<<dim3(8, 32), 256, 0, stream>>>(Xbf, WkT, KVp, 4096, 1024, 3584);

  // rope + pack (scale folded into Q)
  rope_pack<<<28672, 256, 0, stream>>>(Qp, tab, Qbf, 28, 3584, 0.08838834764831845f);
  rope_pack<<<4096, 256, 0, stream>>>(KVp, tab, Kbf, 4, 1024, 1.0f);
  pack_vt<<<dim3(64, 4, 8), 256, 0, stream>>>(KVp, Vtb, 1024, 512);

  // attention
  attn_kernel<<<dim3(16, 28, 2), 512, 0, stream>>>(Qbf, Kbf, Vtb, AO);

  // output projection
  gemm_bt<<<dim3(28, 32), 256, 0, stream>>>(AO, WoT, out, 4096, 3584, 3584);
}

// Round 6
// 642.852 us; speedup vs baseline: 1.6905x; 1.1521x over previous
//
#include <hip/hip_runtime.h>
#include <hip/hip_bf16.h>

typedef __attribute__((ext_vector_type(4))) float f32x4;
typedef __attribute__((ext_vector_type(8))) short s16x8;
typedef __attribute__((ext_vector_type(4))) short s16x4;
typedef unsigned short u16;

// ---------- helpers ----------
__device__ __forceinline__ u16 f2bf(float f) {
  union { float f; unsigned int u; } v; v.f = f;
  unsigned int r = v.u + 0x7fffu + ((v.u >> 16) & 1u);  // RNE
  return (u16)(r >> 16);
}

__device__ __forceinline__ void gload_lds16(const void* g, void* l) {
  __builtin_amdgcn_global_load_lds(
      (const __attribute__((address_space(1))) void*)g,
      (__attribute__((address_space(3))) void*)l, 16, 0, 0);
}

// ---------- elementwise f32 -> bf16 (vectorized) ----------
__global__ __launch_bounds__(256) void cvt_bf16(const float* __restrict__ in,
                                                u16* __restrict__ outp, int nquad) {
  int i = blockIdx.x * 256 + threadIdx.x;
  if (i >= nquad) return;
  f32x4 v = *(const f32x4*)(in + (size_t)i * 4);
  s16x4 o;
  o.x = (short)f2bf(v.x); o.y = (short)f2bf(v.y);
  o.z = (short)f2bf(v.z); o.w = (short)f2bf(v.w);
  *(s16x4*)(outp + (size_t)i * 4) = o;
}

// ---------- transpose + convert: in (R x C) f32 row-major -> out (C x R) bf16 ----------
__global__ __launch_bounds__(256) void transpose_cvt(const float* __restrict__ in,
                                                     u16* __restrict__ outp, int R, int C) {
  __shared__ float t[32][33];
  int c0 = blockIdx.x * 32, r0 = blockIdx.y * 32;
  int tx = threadIdx.x & 31, ty = threadIdx.x >> 5;  // 32 x 8
#pragma unroll
  for (int i = 0; i < 32; i += 8) t[ty + i][tx] = in[(size_t)(r0 + ty + i) * C + c0 + tx];
  __syncthreads();
#pragma unroll
  for (int i = 0; i < 32; i += 8)
    outp[(size_t)(c0 + ty + i) * R + r0 + tx] = f2bf(t[tx][ty + i]);
}

// ---------- RoPE table (matches the reference's interleaved-then-split layout) ----------
__global__ void rope_table(float2* __restrict__ tab) {
  int p = blockIdx.x, e = threadIdx.x;
  int j = e >> 1;
  float f1 = powf(1.0e6f, -(float)j / 64.0f);
  float f2 = powf(1.0e6f, -(float)(j + 32) / 64.0f);
  float a1 = (float)p * f1, a2 = (float)p * f2;
  float S = (e & 1) ? cosf(a1) : sinf(a1);
  float C = (e & 1) ? cosf(a2) : sinf(a2);
  tab[p * 64 + e] = make_float2(S, C);
}

// ---------- RoPE + head-pack: P (B*S x ldp) f32 -> out [b][h][s][128] bf16 ----------
__global__ __launch_bounds__(256) void rope_pack(const float* __restrict__ P,
                                                 const float2* __restrict__ tab,
                                                 u16* __restrict__ outp, int nh, int ldp,
                                                 float scale) {
  int idx = blockIdx.x * 4 + (threadIdx.x >> 6);  // over (b*nh+h)*2048+s
  int e = threadIdx.x & 63;
  int s = idx & 2047;
  int bh = idx >> 11;
  int b = bh / nh, h = bh - b * nh;
  size_t prow = ((size_t)(b * 2048 + s)) * (size_t)ldp + (size_t)h * 128;
  float x1 = P[prow + e], x2 = P[prow + e + 64];
  float2 t = tab[s * 64 + e];
  float o1 = (x1 * t.y - x2 * t.x) * scale;
  float o2 = (x2 * t.y + x1 * t.x) * scale;
  size_t orow = (size_t)idx * 128;
  outp[orow + e] = f2bf(o1);
  outp[orow + e + 64] = f2bf(o2);
}

// ---------- V pack+transpose: KVp rows (stride ldp, V at col off) -> Vt [b][kh][128][S] bf16 ----------
__global__ __launch_bounds__(256) void pack_vt(const float* __restrict__ Vp,
                                               u16* __restrict__ Vt, int ldp, int coff) {
  __shared__ float t[32][33];
  int bk = blockIdx.z;               // b*4+kh
  int b = bk >> 2, kh = bk & 3;
  int s0 = blockIdx.x * 32, d0 = blockIdx.y * 32;
  int tx = threadIdx.x & 31, ty = threadIdx.x >> 5;
  const float* in = Vp + (size_t)(b * 2048) * ldp + coff + kh * 128;
#pragma unroll
  for (int i = 0; i < 32; i += 8) t[ty + i][tx] = in[(size_t)(s0 + ty + i) * ldp + d0 + tx];
  __syncthreads();
  u16* outp = Vt + (size_t)bk * 128 * 2048;
#pragma unroll
  for (int i = 0; i < 32; i += 8)
    outp[(size_t)(d0 + ty + i) * 2048 + s0 + tx] = f2bf(t[tx][ty + i]);
}

// ---------- GEMM: C (MxN f32) = A (MxK bf16) * BT (NxK bf16)^T ; 128x128 tile ----------
__global__ __launch_bounds__(256) void gemm_bt(const u16* __restrict__ A,
                                               const u16* __restrict__ BT,
                                               float* __restrict__ C, int M, int N, int K) {
  __shared__ u16 lA[128 * 32];
  __shared__ u16 lB[128 * 32];
  const int tid = threadIdx.x;
  const int lane = tid & 63, wave = tid >> 6;
  const int bm = blockIdx.y * 128, bn = blockIdx.x * 128;
  const int wr = (wave >> 1) * 64, wc = (wave & 1) * 64;
  const int r = lane & 15, g = lane >> 4;

  f32x4 acc[4][4];
#pragma unroll
  for (int i = 0; i < 4; i++)
#pragma unroll
    for (int j = 0; j < 4; j++) acc[i][j] = (f32x4){0.f, 0.f, 0.f, 0.f};

  const int o0 = wave * 2048 + lane * 16;
  const int row0 = o0 >> 6, cb0 = (o0 & 63) >> 1;
  const int o1 = o0 + 1024;
  const int row1 = o1 >> 6, cb1 = (o1 & 63) >> 1;
  const u16* a0 = A + (size_t)(bm + row0) * K + cb0;
  const u16* a1 = A + (size_t)(bm + row1) * K + cb1;
  const u16* b0 = BT + (size_t)(bn + row0) * K + cb0;
  const u16* b1 = BT + (size_t)(bn + row1) * K + cb1;
  u16* lA0 = lA + wave * 2 * 512; u16* lA1 = lA + (wave * 2 + 1) * 512;
  u16* lB0 = lB + wave * 2 * 512; u16* lB1 = lB + (wave * 2 + 1) * 512;

  for (int kt = 0; kt < K; kt += 32) {
    __syncthreads();
    gload_lds16(a0 + kt, lA0);
    gload_lds16(a1 + kt, lA1);
    gload_lds16(b0 + kt, lB0);
    gload_lds16(b1 + kt, lB1);
    __syncthreads();
    s16x8 af[4], bf[4];
#pragma unroll
    for (int m2 = 0; m2 < 4; m2++) af[m2] = *(const s16x8*)(lA + (wr + m2 * 16 + r) * 32 + g * 8);
#pragma unroll
    for (int n2 = 0; n2 < 4; n2++) bf[n2] = *(const s16x8*)(lB + (wc + n2 * 16 + r) * 32 + g * 8);
#pragma unroll
    for (int m2 = 0; m2 < 4; m2++)
#pragma unroll
      for (int n2 = 0; n2 < 4; n2++)
        acc[m2][n2] = __builtin_amdgcn_mfma_f32_16x16x32_bf16(af[m2], bf[n2], acc[m2][n2], 0, 0, 0);
  }
#pragma unroll
  for (int m2 = 0; m2 < 4; m2++)
#pragma unroll
    for (int n2 = 0; n2 < 4; n2++)
#pragma unroll
      for (int jj = 0; jj < 4; jj++)
        C[(size_t)(bm + wr + m2 * 16 + g * 4 + jj) * N + (bn + wc + n2 * 16 + r)] =
            acc[m2][n2][jj];
}

// ---------- causal GQA flash attention, 8-wave blocks (QBLK=128), LDS-staged K/V ----------
// Q [b][28][S][128] bf16 (pre-scaled), K [b][4][S][128] bf16, Vt [b][4][128][S] bf16
// AO (B*S x 3584) bf16.  KVBLK=32.
// Work-uniform pairing: block p handles q-tiles {p, 15-p} sequentially (68 kv-tiles
// each, no causal tail).  Counted-vmcnt double-buffer: next tile's 2 DMA loads stay
// in flight across raw s_barriers (no vmcnt(0) drain in the loop).
__global__ __launch_bounds__(512, 4) void attn_kernel(const u16* __restrict__ Q,
                                                      const u16* __restrict__ K,
                                                      const u16* __restrict__ Vt,
                                                      u16* __restrict__ AO) {
  constexpr int S = 2048, NH = 28, NKV = 4, D = 128;
  __shared__ u16 Kl[2][32 * 128];  // [row][256B], stored byte ^= (row&7)<<4
  __shared__ u16 Vl[2][32 * 128];  // [d][64B],   stored byte ^= ((d>>1)&7)<<4
  const int tid = threadIdx.x;
  const int lane = tid & 63, w = tid >> 6;
  const int r = lane & 15, g = lane >> 4;
  const int pp = blockIdx.x, h = blockIdx.y, b = blockIdx.z;
  const int kh = h & 3;
  const u16* Kb = K + ((size_t)(b * NKV + kh) * S) * D;
  const u16* Vb = Vt + ((size_t)(b * NKV + kh) * D) * S;

  // staging: 512 threads x 16B = 8KB tile each for K and V.
  // LDS dest linear at byte o = tid*16; global source pre-swizzled (involutions).
  const int o = tid * 16;
  const int krow = o >> 8;
  const int kcol = ((o & 255) ^ ((krow & 7) << 4)) >> 1;
  const u16* sK = Kb + (size_t)krow * D + kcol;
  const int pb = o ^ (((o >> 7) & 7) << 4);
  const u16* sV = Vb + (size_t)(pb >> 6) * S + ((pb & 63) >> 1);

#pragma unroll 1
  for (int seg = 0; seg < 2; ++seg) {
    const int qt = seg ? (15 - pp) : pp;
    const int q0 = qt * 128 + w * 16;
    const u16* Qb = Q + ((size_t)(b * NH + h) * S + q0) * D;

    s16x8 qf[4];
#pragma unroll
    for (int kb = 0; kb < 4; kb++)
      qf[kb] = *(const s16x8*)(Qb + (size_t)r * D + kb * 32 + g * 8);

    f32x4 o8[8];
#pragma unroll
    for (int c = 0; c < 8; c++) o8[c] = (f32x4){0.f, 0.f, 0.f, 0.f};
    float m = -1e30f, lsum = 0.f;
    const int qg = q0 + r;
    const int NT = 4 * qt + 4;

    // prologue: issue tile 0 loads (2 per thread)
    gload_lds16(sK, (u16*)Kl[0] + tid * 8);
    gload_lds16(sV, (u16*)Vl[0] + tid * 8);

    int cur = 0;
#pragma unroll 1
    for (int t = 0; t < NT; ++t) {
      const int j = t * 32;
      if (t + 1 < NT) {
        const int jn = j + 32;
        gload_lds16(sK + (size_t)jn * D, (u16*)Kl[cur ^ 1] + tid * 8);
        gload_lds16(sV + jn, (u16*)Vl[cur ^ 1] + tid * 8);
        asm volatile("s_waitcnt vmcnt(2)" ::: "memory");  // current tile's loads done
      } else {
        asm volatile("s_waitcnt vmcnt(0)" ::: "memory");
      }
      __builtin_amdgcn_s_barrier();   // all waves' staging of buf[cur] visible
      __builtin_amdgcn_sched_barrier(0);
      if (j <= q0 + 15) {  // wave-uniform active check
        // ---- QK^T (swapped): lane holds P[kv=16*hi+g*4+jj][q=r] ----
        f32x4 st0 = (f32x4){0.f, 0.f, 0.f, 0.f};
        f32x4 st1 = (f32x4){0.f, 0.f, 0.f, 0.f};
        const int swz = (r & 7) << 4;
        const char* Kc = (const char*)Kl[cur];
        __builtin_amdgcn_s_setprio(1);
#pragma unroll
        for (int kb = 0; kb < 4; kb++) {
          int cb = (kb * 64 + g * 16) ^ swz;
          s16x8 kf = *(const s16x8*)(Kc + r * 256 + cb);
          st0 = __builtin_amdgcn_mfma_f32_16x16x32_bf16(kf, qf[kb], st0, 0, 0, 0);
        }
#pragma unroll
        for (int kb = 0; kb < 4; kb++) {
          int cb = (kb * 64 + g * 16) ^ swz;
          s16x8 kf = *(const s16x8*)(Kc + (r + 16) * 256 + cb);
          st1 = __builtin_amdgcn_mfma_f32_16x16x32_bf16(kf, qf[kb], st1, 0, 0, 0);
        }
        __builtin_amdgcn_s_setprio(0);
        float s8v[8];
        if (j + 31 <= q0) {  // fully unmasked tile
#pragma unroll
          for (int jj = 0; jj < 4; jj++) { s8v[jj] = st0[jj]; s8v[jj + 4] = st1[jj]; }
        } else {
#pragma unroll
          for (int jj = 0; jj < 4; jj++) {
            int kv0 = j + g * 4 + jj;
            s8v[jj] = (kv0 > qg) ? -1e30f : st0[jj];
            s8v[jj + 4] = (kv0 + 16 > qg) ? -1e30f : st1[jj];
          }
        }
        // ---- online softmax (row = q = r, reduce over g-lanes) ----
        float pm = fmaxf(fmaxf(fmaxf(s8v[0], s8v[1]), fmaxf(s8v[2], s8v[3])),
                         fmaxf(fmaxf(s8v[4], s8v[5]), fmaxf(s8v[6], s8v[7])));
        pm = fmaxf(pm, __shfl_xor(pm, 16));
        pm = fmaxf(pm, __shfl_xor(pm, 32));
        // defer-max (T13): skip rescale when max growth <= 8 across the wave
        const bool defer = __all(pm <= m + 8.f);
        float mnew, fr;
        if (defer) { mnew = m; fr = 1.f; }
        else { mnew = fmaxf(m, pm); fr = __expf(m - mnew); }
        float pv[8], psum = 0.f;
#pragma unroll
        for (int i2 = 0; i2 < 8; i2++) { pv[i2] = __expf(s8v[i2] - mnew); psum += pv[i2]; }
        psum += __shfl_xor(psum, 16);
        psum += __shfl_xor(psum, 32);
        lsum = lsum * fr + psum;
        m = mnew;
        // ---- P -> bf16 ----
        // lane (r,g) holds pk[2*hi+p2] = P[q=r][kvl=16*hi+4g+2*p2 .. +1]
        unsigned pk[4];
#pragma unroll
        for (int i2 = 0; i2 < 4; i2++) {
          __hip_bfloat162 hv = __float22bfloat162_rn(make_float2(pv[2 * i2], pv[2 * i2 + 1]));
          union { __hip_bfloat162 h; unsigned u; } cv; cv.h = hv; pk[i2] = cv.u;
        }
        // ---- redistribute to A-fragment layout: dest (r,g) slot d needs
        //      pk[2*(g>>1)+(d&1)] from lane r + 32*(g&1) + 16*(d>>1). ----
        int L0 = r + ((g & 1) << 5);
        unsigned a0 = (unsigned)__shfl((int)pk[0], L0);
        unsigned a1 = (unsigned)__shfl((int)pk[1], L0);
        unsigned a2 = (unsigned)__shfl((int)pk[2], L0);
        unsigned a3 = (unsigned)__shfl((int)pk[3], L0);
        unsigned b0 = (unsigned)__shfl((int)pk[0], L0 + 16);
        unsigned b1 = (unsigned)__shfl((int)pk[1], L0 + 16);
        unsigned b2 = (unsigned)__shfl((int)pk[2], L0 + 16);
        unsigned b3 = (unsigned)__shfl((int)pk[3], L0 + 16);
        union { unsigned u[4]; s16x8 v; } pu;
        pu.u[0] = (g < 2) ? a0 : a2;
        pu.u[1] = (g < 2) ? a1 : a3;
        pu.u[2] = (g < 2) ? b0 : b2;
        pu.u[3] = (g < 2) ? b1 : b3;
        s16x8 pa = pu.v;
        float fB[4];
        if (!defer) {
#pragma unroll
          for (int jj = 0; jj < 4; jj++) fB[jj] = __shfl(fr, g * 4 + jj);
        }
        // ---- PV ----
        const char* Vc = (const char*)Vl[cur];
        __builtin_amdgcn_s_setprio(1);
#pragma unroll
        for (int c = 0; c < 8; c++) {
          int pbyte = (c * 16 + r) * 64 + g * 16;
          int vaddr = pbyte ^ ((r >> 1) << 4);
          s16x8 vf = *(const s16x8*)(Vc + vaddr);
          f32x4 oc = o8[c];
          if (!defer) { oc.x *= fB[0]; oc.y *= fB[1]; oc.z *= fB[2]; oc.w *= fB[3]; }
          o8[c] = __builtin_amdgcn_mfma_f32_16x16x32_bf16(pa, vf, oc, 0, 0, 0);
        }
        __builtin_amdgcn_s_setprio(0);
      }
      __builtin_amdgcn_s_barrier();   // all reads of buf[cur] retired
      cur ^= 1;
    }

    float lB[4];
#pragma unroll
    for (int jj = 0; jj < 4; jj++) lB[jj] = __shfl(lsum, g * 4 + jj);
#pragma unroll
    for (int c = 0; c < 8; c++)
#pragma unroll
      for (int jj = 0; jj < 4; jj++) {
        float val = o8[c][jj] / lB[jj];
        AO[(size_t)(b * S + q0 + g * 4 + jj) * 3584 + h * 128 + c * 16 + r] = f2bf(val);
      }
  }
}

// ---------- workspace layout (bytes) ----------
static const size_t OFF_XBF = 0;            // 4096x3584 bf16
static const size_t OFF_WQT = 29360128;     // 3584x3584 bf16
static const size_t OFF_WKT = 55050240;     // 512x3584 bf16   (contiguous with WVT ->
static const size_t OFF_WVT = 58720256;     // 512x3584 bf16    combined [1024][3584])
static const size_t OFF_WOT = 62390272;     // 3584x3584 bf16
static const size_t OFF_TAB = 88080384;     // 2048x64 float2
static const size_t OFF_QBF = 89128960;     // [2][28][2048][128] bf16
static const size_t OFF_KBF = 118489088;    // [2][4][2048][128] bf16
static const size_t OFF_VT  = 122683392;    // [2][4][128][2048] bf16
static const size_t OFF_QP  = 126877696;    // 4096x3584 f32 (reused: AO bf16)
static const size_t OFF_KVP = 185597952;    // 4096x1024 f32
// total: 202375168 bytes

extern "C" void kernel_launch(void* const* d_in, const int* in_sizes, int n_in,
                              void* d_out, int out_size, void* d_ws, size_t ws_size,
                              hipStream_t stream) {
  const float* X  = (const float*)d_in[0];
  const float* Wq = (const float*)d_in[1];
  const float* Wk = (const float*)d_in[2];
  const float* Wv = (const float*)d_in[3];
  const float* Wo = (const float*)d_in[4];
  float* out = (float*)d_out;
  char* ws = (char*)d_ws;

  u16* Xbf = (u16*)(ws + OFF_XBF);
  u16* WqT = (u16*)(ws + OFF_WQT);
  u16* WkT = (u16*)(ws + OFF_WKT);
  u16* WvT = (u16*)(ws + OFF_WVT);
  u16* WoT = (u16*)(ws + OFF_WOT);
  float2* tab = (float2*)(ws + OFF_TAB);
  u16* Qbf = (u16*)(ws + OFF_QBF);
  u16* Kbf = (u16*)(ws + OFF_KBF);
  u16* Vtb = (u16*)(ws + OFF_VT);
  float* Qp = (float*)(ws + OFF_QP);
  float* KVp = (float*)(ws + OFF_KVP);
  u16* AO  = (u16*)(ws + OFF_QP);  // reuse Qp region after rope_pack

  // conversions
  cvt_bf16<<<14336, 256, 0, stream>>>(X, Xbf, 3670016);
  transpose_cvt<<<dim3(112, 112), 256, 0, stream>>>(Wq, WqT, 3584, 3584);
  transpose_cvt<<<dim3(16, 112), 256, 0, stream>>>(Wk, WkT, 3584, 512);
  transpose_cvt<<<dim3(16, 112), 256, 0, stream>>>(Wv, WvT, 3584, 512);
  transpose_cvt<<<dim3(112, 112), 256, 0, stream>>>(Wo, WoT, 3584, 3584);
  rope_table<<<2048, 64, 0, stream>>>(tab);

  // projections (K and V fused: BT = [WkT ; WvT] is contiguous, N=1024)
  gemm_bt<<<dim3(28, 32), 256, 0, stream>>>(Xbf, WqT, Qp, 4096, 3584, 3584);
  gemm_bt<<<dim3(8, 32), 256, 0, stream>>>(Xbf, WkT, KVp, 4096, 1024, 3584);

  // rope + pack (scale folded into Q)
  rope_pack<<<28672, 256, 0, stream>>>(Qp, tab, Qbf, 28, 3584, 0.08838834764831845f);
  rope_pack<<<4096, 256, 0, stream>>>(KVp, tab, Kbf, 4, 1024, 1.0f);
  pack_vt<<<dim3(64, 4, 8), 256, 0, stream>>>(KVp, Vtb, 1024, 512);

  // attention (8 work-uniform q-tile pairs)
  attn_kernel<<<dim3(8, 28, 2), 512, 0, stream>>>(Qbf, Kbf, Vtb, AO);

  // output projection
  gemm_bt<<<dim3(28, 32), 256, 0, stream>>>(AO, WoT, out, 4096, 3584, 3584);
}

// Round 7
// 513.410 us; speedup vs baseline: 2.1167x; 1.2521x over previous
//
#include <hip/hip_runtime.h>
#include <hip/hip_bf16.h>

typedef __attribute__((ext_vector_type(4))) float f32x4;
typedef __attribute__((ext_vector_type(8))) short s16x8;
typedef __attribute__((ext_vector_type(4))) short s16x4;
typedef unsigned short u16;

// ---------- helpers ----------
__device__ __forceinline__ u16 f2bf(float f) {
  union { float f; unsigned int u; } v; v.f = f;
  unsigned int r = v.u + 0x7fffu + ((v.u >> 16) & 1u);  // RNE
  return (u16)(r >> 16);
}

__device__ __forceinline__ void gload_lds16(const void* g, void* l) {
  __builtin_amdgcn_global_load_lds(
      (const __attribute__((address_space(1))) void*)g,
      (__attribute__((address_space(3))) void*)l, 16, 0, 0);
}

// ---------- elementwise f32 -> bf16 (vectorized) ----------
__global__ __launch_bounds__(256) void cvt_bf16(const float* __restrict__ in,
                                                u16* __restrict__ outp, int nquad) {
  int i = blockIdx.x * 256 + threadIdx.x;
  if (i >= nquad) return;
  f32x4 v = *(const f32x4*)(in + (size_t)i * 4);
  s16x4 o;
  o.x = (short)f2bf(v.x); o.y = (short)f2bf(v.y);
  o.z = (short)f2bf(v.z); o.w = (short)f2bf(v.w);
  *(s16x4*)(outp + (size_t)i * 4) = o;
}

// ---------- transpose + convert: in (R x C) f32 row-major -> out (C x R) bf16 ----------
__global__ __launch_bounds__(256) void transpose_cvt(const float* __restrict__ in,
                                                     u16* __restrict__ outp, int R, int C) {
  __shared__ float t[32][33];
  int c0 = blockIdx.x * 32, r0 = blockIdx.y * 32;
  int tx = threadIdx.x & 31, ty = threadIdx.x >> 5;  // 32 x 8
#pragma unroll
  for (int i = 0; i < 32; i += 8) t[ty + i][tx] = in[(size_t)(r0 + ty + i) * C + c0 + tx];
  __syncthreads();
#pragma unroll
  for (int i = 0; i < 32; i += 8)
    outp[(size_t)(c0 + ty + i) * R + r0 + tx] = f2bf(t[tx][ty + i]);
}

// ---------- RoPE table (matches the reference's interleaved-then-split layout) ----------
__global__ void rope_table(float2* __restrict__ tab) {
  int p = blockIdx.x, e = threadIdx.x;
  int j = e >> 1;
  float f1 = powf(1.0e6f, -(float)j / 64.0f);
  float f2 = powf(1.0e6f, -(float)(j + 32) / 64.0f);
  float a1 = (float)p * f1, a2 = (float)p * f2;
  float S = (e & 1) ? cosf(a1) : sinf(a1);
  float C = (e & 1) ? cosf(a2) : sinf(a2);
  tab[p * 64 + e] = make_float2(S, C);
}

// ---------- RoPE + head-pack: P (B*S x ldp) f32 -> out [b][h][s][128] bf16 ----------
__global__ __launch_bounds__(256) void rope_pack(const float* __restrict__ P,
                                                 const float2* __restrict__ tab,
                                                 u16* __restrict__ outp, int nh, int ldp,
                                                 float scale) {
  int idx = blockIdx.x * 4 + (threadIdx.x >> 6);  // over (b*nh+h)*2048+s
  int e = threadIdx.x & 63;
  int s = idx & 2047;
  int bh = idx >> 11;
  int b = bh / nh, h = bh - b * nh;
  size_t prow = ((size_t)(b * 2048 + s)) * (size_t)ldp + (size_t)h * 128;
  float x1 = P[prow + e], x2 = P[prow + e + 64];
  float2 t = tab[s * 64 + e];
  float o1 = (x1 * t.y - x2 * t.x) * scale;
  float o2 = (x2 * t.y + x1 * t.x) * scale;
  size_t orow = (size_t)idx * 128;
  outp[orow + e] = f2bf(o1);
  outp[orow + e + 64] = f2bf(o2);
}

// ---------- V pack+transpose: KVp rows (stride ldp, V at col off) -> Vt [b][kh][128][S] bf16 ----------
__global__ __launch_bounds__(256) void pack_vt(const float* __restrict__ Vp,
                                               u16* __restrict__ Vt, int ldp, int coff) {
  __shared__ float t[32][33];
  int bk = blockIdx.z;               // b*4+kh
  int b = bk >> 2, kh = bk & 3;
  int s0 = blockIdx.x * 32, d0 = blockIdx.y * 32;
  int tx = threadIdx.x & 31, ty = threadIdx.x >> 5;
  const float* in = Vp + (size_t)(b * 2048) * ldp + coff + kh * 128;
#pragma unroll
  for (int i = 0; i < 32; i += 8) t[ty + i][tx] = in[(size_t)(s0 + ty + i) * ldp + d0 + tx];
  __syncthreads();
  u16* outp = Vt + (size_t)bk * 128 * 2048;
#pragma unroll
  for (int i = 0; i < 32; i += 8)
    outp[(size_t)(d0 + ty + i) * 2048 + s0 + tx] = f2bf(t[tx][ty + i]);
}

// ---------- GEMM (small-N path): C = A * BT^T ; 128x128 tile, m97 structure ----------
__global__ __launch_bounds__(256) void gemm_bt(const u16* __restrict__ A,
                                               const u16* __restrict__ BT,
                                               float* __restrict__ C, int M, int N, int K) {
  __shared__ u16 lA[128 * 32];
  __shared__ u16 lB[128 * 32];
  const int tid = threadIdx.x;
  const int lane = tid & 63, wave = tid >> 6;
  const int bm = blockIdx.y * 128, bn = blockIdx.x * 128;
  const int wr = (wave >> 1) * 64, wc = (wave & 1) * 64;
  const int r = lane & 15, g = lane >> 4;

  f32x4 acc[4][4];
#pragma unroll
  for (int i = 0; i < 4; i++)
#pragma unroll
    for (int j = 0; j < 4; j++) acc[i][j] = (f32x4){0.f, 0.f, 0.f, 0.f};

  const int o0 = wave * 2048 + lane * 16;
  const int row0 = o0 >> 6, cb0 = (o0 & 63) >> 1;
  const int o1 = o0 + 1024;
  const int row1 = o1 >> 6, cb1 = (o1 & 63) >> 1;
  const u16* a0 = A + (size_t)(bm + row0) * K + cb0;
  const u16* a1 = A + (size_t)(bm + row1) * K + cb1;
  const u16* b0 = BT + (size_t)(bn + row0) * K + cb0;
  const u16* b1 = BT + (size_t)(bn + row1) * K + cb1;
  u16* lA0 = lA + wave * 2 * 512; u16* lA1 = lA + (wave * 2 + 1) * 512;
  u16* lB0 = lB + wave * 2 * 512; u16* lB1 = lB + (wave * 2 + 1) * 512;

  for (int kt = 0; kt < K; kt += 32) {
    __syncthreads();
    gload_lds16(a0 + kt, lA0);
    gload_lds16(a1 + kt, lA1);
    gload_lds16(b0 + kt, lB0);
    gload_lds16(b1 + kt, lB1);
    __syncthreads();
    s16x8 af[4], bf[4];
#pragma unroll
    for (int m2 = 0; m2 < 4; m2++) af[m2] = *(const s16x8*)(lA + (wr + m2 * 16 + r) * 32 + g * 8);
#pragma unroll
    for (int n2 = 0; n2 < 4; n2++) bf[n2] = *(const s16x8*)(lB + (wc + n2 * 16 + r) * 32 + g * 8);
#pragma unroll
    for (int m2 = 0; m2 < 4; m2++)
#pragma unroll
      for (int n2 = 0; n2 < 4; n2++)
        acc[m2][n2] = __builtin_amdgcn_mfma_f32_16x16x32_bf16(af[m2], bf[n2], acc[m2][n2], 0, 0, 0);
  }
#pragma unroll
  for (int m2 = 0; m2 < 4; m2++)
#pragma unroll
    for (int n2 = 0; n2 < 4; n2++)
#pragma unroll
      for (int jj = 0; jj < 4; jj++)
        C[(size_t)(bm + wr + m2 * 16 + g * 4 + jj) * N + (bn + wc + n2 * 16 + r)] =
            acc[m2][n2][jj];
}

// ---------- GEMM (big path): 256x256 tile, BK=64, 8 waves, 4-phase interleave,
//            XOR-swizzled LDS, counted vmcnt(2) double-buffer (T2+T3+T4+T5) ----------
// 128 KiB dynamic LDS: [buf0 A 32K][buf1 A 32K][buf0 B 32K][buf1 B 32K] (u16 elems).
// Swizzle (both sides, involution): LDS linear byte o holds row=o>>7,
// colbyte=(o&127)^((row&7)<<4); ds_read addr=(row*128+cb)^((row&7)<<4).
__global__ __launch_bounds__(512, 2) void gemm256(const u16* __restrict__ A,
                                                  const u16* __restrict__ BT,
                                                  float* __restrict__ C,
                                                  int M, int N, int K) {
  extern __shared__ u16 sm[];
  const int tid = threadIdx.x;
  const int lane = tid & 63, w = tid >> 6;
  const int wm = w >> 2, wn = w & 3;        // 2 x 4 wave grid
  const int r = lane & 15, g = lane >> 4;
  const int bm = blockIdx.y * 256, bn = blockIdx.x * 256;

  f32x4 acc[8][4];
#pragma unroll
  for (int mf = 0; mf < 8; mf++)
#pragma unroll
    for (int nf = 0; nf < 4; nf++) acc[mf][nf] = (f32x4){0.f, 0.f, 0.f, 0.f};

  // staging sources (pre-swizzled): thread covers linear bytes o = i*8192 + tid*16
  const int row_s = tid >> 3;                                   // 0..63
  const int col_s = ((((tid & 7) << 4) ^ ((row_s & 7) << 4)) >> 1);  // elements
  const u16* sAg[4]; const u16* sBg[4];
#pragma unroll
  for (int i = 0; i < 4; i++) {
    sAg[i] = A  + (size_t)(bm + i * 64 + row_s) * K + col_s;
    sBg[i] = BT + (size_t)(bn + i * 64 + row_s) * K + col_s;
  }
  // LDS dest bases (wave-uniform; HW adds lane*16B): elem off = i*4096 + w*512

  // prologue: stage tile 0 into buffer 0 (8 loads/thread)
#pragma unroll
  for (int i = 0; i < 4; i++) gload_lds16(sAg[i], sm + i * 4096 + w * 512);
#pragma unroll
  for (int i = 0; i < 4; i++) gload_lds16(sBg[i], sm + 32768 + i * 4096 + w * 512);

  const int NT = K >> 6;
  const int swz = (r & 7) << 4;
#pragma unroll 1
  for (int t = 0; t < NT; ++t) {
    const int p = t & 1;
    const u16* LA = sm + p * 16384;
    const u16* LB = sm + 32768 + p * 16384;
    u16* SA = sm + (p ^ 1) * 16384;
    u16* SB = sm + 32768 + (p ^ 1) * 16384;
    const int ktn = (t + 1 < NT) ? (t + 1) * 64 : 0;  // last iter: dummy re-read, discarded

    __builtin_amdgcn_s_barrier();           // (a) all reads of buf[p^1] retired
    gload_lds16(sAg[0] + ktn, SA + 0 * 4096 + w * 512);
    gload_lds16(sAg[1] + ktn, SA + 1 * 4096 + w * 512);
    asm volatile("s_waitcnt vmcnt(2)" ::: "memory");  // drain buf[p]'s 8; keep 2 in flight
    __builtin_amdgcn_s_barrier();           // (b) buf[p] staged for all waves
    __builtin_amdgcn_sched_barrier(0);

    const char* Ac = (const char*)LA;
    const char* Bc = (const char*)LB;
    // B fragments for the whole K-tile (8 x ds_read_b128)
    s16x8 bf[4][2];
#pragma unroll
    for (int nf = 0; nf < 4; nf++)
#pragma unroll
      for (int ks = 0; ks < 2; ks++) {
        int row = wn * 64 + nf * 16 + r;
        bf[nf][ks] = *(const s16x8*)(Bc + ((row * 128 + ks * 64 + g * 16) ^ swz));
      }
    // 4 phases: each {2 stage-issues} || {4 A ds_reads} || {16 MFMA}
#pragma unroll
    for (int ph = 0; ph < 4; ph++) {
      if (ph == 1) {
        gload_lds16(sAg[2] + ktn, SA + 2 * 4096 + w * 512);
        gload_lds16(sAg[3] + ktn, SA + 3 * 4096 + w * 512);
      } else if (ph == 2) {
        gload_lds16(sBg[0] + ktn, SB + 0 * 4096 + w * 512);
        gload_lds16(sBg[1] + ktn, SB + 1 * 4096 + w * 512);
      } else if (ph == 3) {
        gload_lds16(sBg[2] + ktn, SB + 2 * 4096 + w * 512);
        gload_lds16(sBg[3] + ktn, SB + 3 * 4096 + w * 512);
      }
      s16x8 af[2][2];
#pragma unroll
      for (int mi = 0; mi < 2; mi++)
#pragma unroll
        for (int ks = 0; ks < 2; ks++) {
          int row = wm * 128 + (ph * 2 + mi) * 16 + r;
          af[mi][ks] = *(const s16x8*)(Ac + ((row * 128 + ks * 64 + g * 16) ^ swz));
        }
      __builtin_amdgcn_s_setprio(1);
#pragma unroll
      for (int mi = 0; mi < 2; mi++)
#pragma unroll
        for (int nf = 0; nf < 4; nf++) {
          acc[ph * 2 + mi][nf] = __builtin_amdgcn_mfma_f32_16x16x32_bf16(
              af[mi][0], bf[nf][0], acc[ph * 2 + mi][nf], 0, 0, 0);
          acc[ph * 2 + mi][nf] = __builtin_amdgcn_mfma_f32_16x16x32_bf16(
              af[mi][1], bf[nf][1], acc[ph * 2 + mi][nf], 0, 0, 0);
        }
      __builtin_amdgcn_s_setprio(0);
    }
  }
  asm volatile("s_waitcnt vmcnt(0)" ::: "memory");  // drain dummy stage before endpgm

#pragma unroll
  for (int mf = 0; mf < 8; mf++)
#pragma unroll
    for (int nf = 0; nf < 4; nf++)
#pragma unroll
      for (int jj = 0; jj < 4; jj++)
        C[(size_t)(bm + wm * 128 + mf * 16 + g * 4 + jj) * N +
          (bn + wn * 64 + nf * 16 + r)] = acc[mf][nf][jj];
}

// ---------- causal GQA flash attention (unchanged from round 6) ----------
__global__ __launch_bounds__(512, 4) void attn_kernel(const u16* __restrict__ Q,
                                                      const u16* __restrict__ K,
                                                      const u16* __restrict__ Vt,
                                                      u16* __restrict__ AO) {
  constexpr int S = 2048, NH = 28, NKV = 4, D = 128;
  __shared__ u16 Kl[2][32 * 128];  // [row][256B], stored byte ^= (row&7)<<4
  __shared__ u16 Vl[2][32 * 128];  // [d][64B],   stored byte ^= ((d>>1)&7)<<4
  const int tid = threadIdx.x;
  const int lane = tid & 63, w = tid >> 6;
  const int r = lane & 15, g = lane >> 4;
  const int pp = blockIdx.x, h = blockIdx.y, b = blockIdx.z;
  const int kh = h & 3;
  const u16* Kb = K + ((size_t)(b * NKV + kh) * S) * D;
  const u16* Vb = Vt + ((size_t)(b * NKV + kh) * D) * S;

  const int o = tid * 16;
  const int krow = o >> 8;
  const int kcol = ((o & 255) ^ ((krow & 7) << 4)) >> 1;
  const u16* sK = Kb + (size_t)krow * D + kcol;
  const int pb = o ^ (((o >> 7) & 7) << 4);
  const u16* sV = Vb + (size_t)(pb >> 6) * S + ((pb & 63) >> 1);

#pragma unroll 1
  for (int seg = 0; seg < 2; ++seg) {
    const int qt = seg ? (15 - pp) : pp;
    const int q0 = qt * 128 + w * 16;
    const u16* Qb = Q + ((size_t)(b * NH + h) * S + q0) * D;

    s16x8 qf[4];
#pragma unroll
    for (int kb = 0; kb < 4; kb++)
      qf[kb] = *(const s16x8*)(Qb + (size_t)r * D + kb * 32 + g * 8);

    f32x4 o8[8];
#pragma unroll
    for (int c = 0; c < 8; c++) o8[c] = (f32x4){0.f, 0.f, 0.f, 0.f};
    float m = -1e30f, lsum = 0.f;
    const int qg = q0 + r;
    const int NT = 4 * qt + 4;

    gload_lds16(sK, (u16*)Kl[0] + tid * 8);
    gload_lds16(sV, (u16*)Vl[0] + tid * 8);

    int cur = 0;
#pragma unroll 1
    for (int t = 0; t < NT; ++t) {
      const int j = t * 32;
      if (t + 1 < NT) {
        const int jn = j + 32;
        gload_lds16(sK + (size_t)jn * D, (u16*)Kl[cur ^ 1] + tid * 8);
        gload_lds16(sV + jn, (u16*)Vl[cur ^ 1] + tid * 8);
        asm volatile("s_waitcnt vmcnt(2)" ::: "memory");
      } else {
        asm volatile("s_waitcnt vmcnt(0)" ::: "memory");
      }
      __builtin_amdgcn_s_barrier();
      __builtin_amdgcn_sched_barrier(0);
      if (j <= q0 + 15) {
        f32x4 st0 = (f32x4){0.f, 0.f, 0.f, 0.f};
        f32x4 st1 = (f32x4){0.f, 0.f, 0.f, 0.f};
        const int swz = (r & 7) << 4;
        const char* Kc = (const char*)Kl[cur];
        __builtin_amdgcn_s_setprio(1);
#pragma unroll
        for (int kb = 0; kb < 4; kb++) {
          int cb = (kb * 64 + g * 16) ^ swz;
          s16x8 kf = *(const s16x8*)(Kc + r * 256 + cb);
          st0 = __builtin_amdgcn_mfma_f32_16x16x32_bf16(kf, qf[kb], st0, 0, 0, 0);
        }
#pragma unroll
        for (int kb = 0; kb < 4; kb++) {
          int cb = (kb * 64 + g * 16) ^ swz;
          s16x8 kf = *(const s16x8*)(Kc + (r + 16) * 256 + cb);
          st1 = __builtin_amdgcn_mfma_f32_16x16x32_bf16(kf, qf[kb], st1, 0, 0, 0);
        }
        __builtin_amdgcn_s_setprio(0);
        float s8v[8];
        if (j + 31 <= q0) {
#pragma unroll
          for (int jj = 0; jj < 4; jj++) { s8v[jj] = st0[jj]; s8v[jj + 4] = st1[jj]; }
        } else {
#pragma unroll
          for (int jj = 0; jj < 4; jj++) {
            int kv0 = j + g * 4 + jj;
            s8v[jj] = (kv0 > qg) ? -1e30f : st0[jj];
            s8v[jj + 4] = (kv0 + 16 > qg) ? -1e30f : st1[jj];
          }
        }
        float pm = fmaxf(fmaxf(fmaxf(s8v[0], s8v[1]), fmaxf(s8v[2], s8v[3])),
                         fmaxf(fmaxf(s8v[4], s8v[5]), fmaxf(s8v[6], s8v[7])));
        pm = fmaxf(pm, __shfl_xor(pm, 16));
        pm = fmaxf(pm, __shfl_xor(pm, 32));
        const bool defer = __all(pm <= m + 8.f);
        float mnew, fr;
        if (defer) { mnew = m; fr = 1.f; }
        else { mnew = fmaxf(m, pm); fr = __expf(m - mnew); }
        float pv[8], psum = 0.f;
#pragma unroll
        for (int i2 = 0; i2 < 8; i2++) { pv[i2] = __expf(s8v[i2] - mnew); psum += pv[i2]; }
        psum += __shfl_xor(psum, 16);
        psum += __shfl_xor(psum, 32);
        lsum = lsum * fr + psum;
        m = mnew;
        unsigned pk[4];
#pragma unroll
        for (int i2 = 0; i2 < 4; i2++) {
          __hip_bfloat162 hv = __float22bfloat162_rn(make_float2(pv[2 * i2], pv[2 * i2 + 1]));
          union { __hip_bfloat162 h; unsigned u; } cv; cv.h = hv; pk[i2] = cv.u;
        }
        int L0 = r + ((g & 1) << 5);
        unsigned a0 = (unsigned)__shfl((int)pk[0], L0);
        unsigned a1 = (unsigned)__shfl((int)pk[1], L0);
        unsigned a2 = (unsigned)__shfl((int)pk[2], L0);
        unsigned a3 = (unsigned)__shfl((int)pk[3], L0);
        unsigned b0 = (unsigned)__shfl((int)pk[0], L0 + 16);
        unsigned b1 = (unsigned)__shfl((int)pk[1], L0 + 16);
        unsigned b2 = (unsigned)__shfl((int)pk[2], L0 + 16);
        unsigned b3 = (unsigned)__shfl((int)pk[3], L0 + 16);
        union { unsigned u[4]; s16x8 v; } pu;
        pu.u[0] = (g < 2) ? a0 : a2;
        pu.u[1] = (g < 2) ? a1 : a3;
        pu.u[2] = (g < 2) ? b0 : b2;
        pu.u[3] = (g < 2) ? b1 : b3;
        s16x8 pa = pu.v;
        float fB[4];
        if (!defer) {
#pragma unroll
          for (int jj = 0; jj < 4; jj++) fB[jj] = __shfl(fr, g * 4 + jj);
        }
        const char* Vc = (const char*)Vl[cur];
        __builtin_amdgcn_s_setprio(1);
#pragma unroll
        for (int c = 0; c < 8; c++) {
          int pbyte = (c * 16 + r) * 64 + g * 16;
          int vaddr = pbyte ^ ((r >> 1) << 4);
          s16x8 vf = *(const s16x8*)(Vc + vaddr);
          f32x4 oc = o8[c];
          if (!defer) { oc.x *= fB[0]; oc.y *= fB[1]; oc.z *= fB[2]; oc.w *= fB[3]; }
          o8[c] = __builtin_amdgcn_mfma_f32_16x16x32_bf16(pa, vf, oc, 0, 0, 0);
        }
        __builtin_amdgcn_s_setprio(0);
      }
      __builtin_amdgcn_s_barrier();
      cur ^= 1;
    }

    float lB[4];
#pragma unroll
    for (int jj = 0; jj < 4; jj++) lB[jj] = __shfl(lsum, g * 4 + jj);
#pragma unroll
    for (int c = 0; c < 8; c++)
#pragma unroll
      for (int jj = 0; jj < 4; jj++) {
        float val = o8[c][jj] / lB[jj];
        AO[(size_t)(b * S + q0 + g * 4 + jj) * 3584 + h * 128 + c * 16 + r] = f2bf(val);
      }
  }
}

// ---------- workspace layout (bytes) ----------
static const size_t OFF_XBF = 0;            // 4096x3584 bf16
static const size_t OFF_WQT = 29360128;     // 3584x3584 bf16
static const size_t OFF_WKT = 55050240;     // 512x3584 bf16   (contiguous with WVT ->
static const size_t OFF_WVT = 58720256;     // 512x3584 bf16    combined [1024][3584])
static const size_t OFF_WOT = 62390272;     // 3584x3584 bf16
static const size_t OFF_TAB = 88080384;     // 2048x64 float2
static const size_t OFF_QBF = 89128960;     // [2][28][2048][128] bf16
static const size_t OFF_KBF = 118489088;    // [2][4][2048][128] bf16
static const size_t OFF_VT  = 122683392;    // [2][4][128][2048] bf16
static const size_t OFF_QP  = 126877696;    // 4096x3584 f32 (reused: AO bf16)
static const size_t OFF_KVP = 185597952;    // 4096x1024 f32
// total: 202375168 bytes

extern "C" void kernel_launch(void* const* d_in, const int* in_sizes, int n_in,
                              void* d_out, int out_size, void* d_ws, size_t ws_size,
                              hipStream_t stream) {
  const float* X  = (const float*)d_in[0];
  const float* Wq = (const float*)d_in[1];
  const float* Wk = (const float*)d_in[2];
  const float* Wv = (const float*)d_in[3];
  const float* Wo = (const float*)d_in[4];
  float* out = (float*)d_out;
  char* ws = (char*)d_ws;

  u16* Xbf = (u16*)(ws + OFF_XBF);
  u16* WqT = (u16*)(ws + OFF_WQT);
  u16* WkT = (u16*)(ws + OFF_WKT);
  u16* WvT = (u16*)(ws + OFF_WVT);
  u16* WoT = (u16*)(ws + OFF_WOT);
  float2* tab = (float2*)(ws + OFF_TAB);
  u16* Qbf = (u16*)(ws + OFF_QBF);
  u16* Kbf = (u16*)(ws + OFF_KBF);
  u16* Vtb = (u16*)(ws + OFF_VT);
  float* Qp = (float*)(ws + OFF_QP);
  float* KVp = (float*)(ws + OFF_KVP);
  u16* AO  = (u16*)(ws + OFF_QP);  // reuse Qp region after rope_pack

  // allow 128 KiB dynamic LDS for gemm256 (idempotent; not a stream op)
  hipFuncSetAttribute((const void*)gemm256,
                      hipFuncAttributeMaxDynamicSharedMemorySize, 131072);

  // conversions
  cvt_bf16<<<14336, 256, 0, stream>>>(X, Xbf, 3670016);
  transpose_cvt<<<dim3(112, 112), 256, 0, stream>>>(Wq, WqT, 3584, 3584);
  transpose_cvt<<<dim3(16, 112), 256, 0, stream>>>(Wk, WkT, 3584, 512);
  transpose_cvt<<<dim3(16, 112), 256, 0, stream>>>(Wv, WvT, 3584, 512);
  transpose_cvt<<<dim3(112, 112), 256, 0, stream>>>(Wo, WoT, 3584, 3584);
  rope_table<<<2048, 64, 0, stream>>>(tab);

  // projections (Q via 256^2 8-phase; K/V fused via 128^2 kernel, N=1024)
  gemm256<<<dim3(14, 16), 512, 131072, stream>>>(Xbf, WqT, Qp, 4096, 3584, 3584);
  gemm_bt<<<dim3(8, 32), 256, 0, stream>>>(Xbf, WkT, KVp, 4096, 1024, 3584);

  // rope + pack (scale folded into Q)
  rope_pack<<<28672, 256, 0, stream>>>(Qp, tab, Qbf, 28, 3584, 0.08838834764831845f);
  rope_pack<<<4096, 256, 0, stream>>>(KVp, tab, Kbf, 4, 1024, 1.0f);
  pack_vt<<<dim3(64, 4, 8), 256, 0, stream>>>(KVp, Vtb, 1024, 512);

  // attention (8 work-uniform q-tile pairs)
  attn_kernel<<<dim3(8, 28, 2), 512, 0, stream>>>(Qbf, Kbf, Vtb, AO);

  // output projection
  gemm256<<<dim3(14, 16), 512, 131072, stream>>>(AO, WoT, out, 4096, 3584, 3584);
}

// Round 8
// 509.994 us; speedup vs baseline: 2.1309x; 1.0067x over previous
//
#include <hip/hip_runtime.h>
#include <hip/hip_bf16.h>

typedef __attribute__((ext_vector_type(4))) float f32x4;
typedef __attribute__((ext_vector_type(8))) short s16x8;
typedef __attribute__((ext_vector_type(4))) short s16x4;
typedef unsigned short u16;

// ---------- helpers ----------
__device__ __forceinline__ u16 f2bf(float f) {
  union { float f; unsigned int u; } v; v.f = f;
  unsigned int r = v.u + 0x7fffu + ((v.u >> 16) & 1u);  // RNE
  return (u16)(r >> 16);
}
__device__ __forceinline__ float bf2f(u16 x) {
  union { unsigned u; float f; } v; v.u = ((unsigned)x) << 16; return v.f;
}

__device__ __forceinline__ void gload_lds16(const void* g, void* l) {
  __builtin_amdgcn_global_load_lds(
      (const __attribute__((address_space(1))) void*)g,
      (__attribute__((address_space(3))) void*)l, 16, 0, 0);
}

// ---------- elementwise f32 -> bf16 (vectorized) ----------
__global__ __launch_bounds__(256) void cvt_bf16(const float* __restrict__ in,
                                                u16* __restrict__ outp, int nquad) {
  int i = blockIdx.x * 256 + threadIdx.x;
  if (i >= nquad) return;
  f32x4 v = *(const f32x4*)(in + (size_t)i * 4);
  s16x4 o;
  o.x = (short)f2bf(v.x); o.y = (short)f2bf(v.y);
  o.z = (short)f2bf(v.z); o.w = (short)f2bf(v.w);
  *(s16x4*)(outp + (size_t)i * 4) = o;
}

// ---------- transpose + convert: in (R x C) f32 row-major -> out (C x R) bf16 ----------
__global__ __launch_bounds__(256) void transpose_cvt(const float* __restrict__ in,
                                                     u16* __restrict__ outp, int R, int C) {
  __shared__ float t[32][33];
  int c0 = blockIdx.x * 32, r0 = blockIdx.y * 32;
  int tx = threadIdx.x & 31, ty = threadIdx.x >> 5;  // 32 x 8
#pragma unroll
  for (int i = 0; i < 32; i += 8) t[ty + i][tx] = in[(size_t)(r0 + ty + i) * C + c0 + tx];
  __syncthreads();
#pragma unroll
  for (int i = 0; i < 32; i += 8)
    outp[(size_t)(c0 + ty + i) * R + r0 + tx] = f2bf(t[tx][ty + i]);
}

// ---------- RoPE table (matches the reference's interleaved-then-split layout) ----------
__global__ void rope_table(float2* __restrict__ tab) {
  int p = blockIdx.x, e = threadIdx.x;
  int j = e >> 1;
  float f1 = powf(1.0e6f, -(float)j / 64.0f);
  float f2 = powf(1.0e6f, -(float)(j + 32) / 64.0f);
  float a1 = (float)p * f1, a2 = (float)p * f2;
  float S = (e & 1) ? cosf(a1) : sinf(a1);
  float C = (e & 1) ? cosf(a2) : sinf(a2);
  tab[p * 64 + e] = make_float2(S, C);
}

// ---------- RoPE + head-pack: P (B*S x ldp, bf16) -> out [b][h][s][128] bf16 ----------
__global__ __launch_bounds__(256) void rope_pack(const u16* __restrict__ P,
                                                 const float2* __restrict__ tab,
                                                 u16* __restrict__ outp, int nh, int ldp,
                                                 int coff, float scale) {
  int idx = blockIdx.x * 4 + (threadIdx.x >> 6);  // over (b*nh+h)*2048+s
  int e = threadIdx.x & 63;
  int s = idx & 2047;
  int bh = idx >> 11;
  int b = bh / nh, h = bh - b * nh;
  size_t prow = ((size_t)(b * 2048 + s)) * (size_t)ldp + coff + (size_t)h * 128;
  float x1 = bf2f(P[prow + e]), x2 = bf2f(P[prow + e + 64]);
  float2 t = tab[s * 64 + e];
  float o1 = (x1 * t.y - x2 * t.x) * scale;
  float o2 = (x2 * t.y + x1 * t.x) * scale;
  size_t orow = (size_t)idx * 128;
  outp[orow + e] = f2bf(o1);
  outp[orow + e + 64] = f2bf(o2);
}

// ---------- V pack+transpose: P rows (bf16, stride ldp, V at col coff) -> Vt [b][kh][128][S] ----------
__global__ __launch_bounds__(256) void pack_vt(const u16* __restrict__ P,
                                               u16* __restrict__ Vt, int ldp, int coff) {
  __shared__ u16 t[32][33];
  int bk = blockIdx.z;               // b*4+kh
  int b = bk >> 2, kh = bk & 3;
  int s0 = blockIdx.x * 32, d0 = blockIdx.y * 32;
  int tx = threadIdx.x & 31, ty = threadIdx.x >> 5;
  const u16* in = P + (size_t)(b * 2048) * ldp + coff + kh * 128;
#pragma unroll
  for (int i = 0; i < 32; i += 8) t[ty + i][tx] = in[(size_t)(s0 + ty + i) * ldp + d0 + tx];
  __syncthreads();
  u16* outp = Vt + (size_t)bk * 128 * 2048;
#pragma unroll
  for (int i = 0; i < 32; i += 8)
    outp[(size_t)(d0 + ty + i) * 2048 + s0 + tx] = t[tx][ty + i];
}

// ---------- GEMM: 256x256 tile, BK=64, 8 waves, 4-phase interleave,
//            XOR-swizzled LDS, counted vmcnt(2) double-buffer (T2+T3+T4+T5) ----------
// 128 KiB dynamic LDS. OUT_BF16 selects bf16 vs f32 C-store.
template <int OUT_BF16>
__global__ __launch_bounds__(512, 2) void gemm256(const u16* __restrict__ A,
                                                  const u16* __restrict__ BT,
                                                  void* __restrict__ Cv,
                                                  int M, int N, int K) {
  extern __shared__ u16 sm[];
  const int tid = threadIdx.x;
  const int lane = tid & 63, w = tid >> 6;
  const int wm = w >> 2, wn = w & 3;        // 2 x 4 wave grid
  const int r = lane & 15, g = lane >> 4;
  const int bm = blockIdx.y * 256, bn = blockIdx.x * 256;

  f32x4 acc[8][4];
#pragma unroll
  for (int mf = 0; mf < 8; mf++)
#pragma unroll
    for (int nf = 0; nf < 4; nf++) acc[mf][nf] = (f32x4){0.f, 0.f, 0.f, 0.f};

  const int row_s = tid >> 3;                                        // 0..63
  const int col_s = ((((tid & 7) << 4) ^ ((row_s & 7) << 4)) >> 1);  // elements
  const u16* sAg[4]; const u16* sBg[4];
#pragma unroll
  for (int i = 0; i < 4; i++) {
    sAg[i] = A  + (size_t)(bm + i * 64 + row_s) * K + col_s;
    sBg[i] = BT + (size_t)(bn + i * 64 + row_s) * K + col_s;
  }

  // prologue: stage tile 0 into buffer 0 (8 loads/thread)
#pragma unroll
  for (int i = 0; i < 4; i++) gload_lds16(sAg[i], sm + i * 4096 + w * 512);
#pragma unroll
  for (int i = 0; i < 4; i++) gload_lds16(sBg[i], sm + 32768 + i * 4096 + w * 512);

  const int NT = K >> 6;
  const int swz = (r & 7) << 4;
#pragma unroll 1
  for (int t = 0; t < NT; ++t) {
    const int p = t & 1;
    const u16* LA = sm + p * 16384;
    const u16* LB = sm + 32768 + p * 16384;
    u16* SA = sm + (p ^ 1) * 16384;
    u16* SB = sm + 32768 + (p ^ 1) * 16384;
    const int ktn = (t + 1 < NT) ? (t + 1) * 64 : 0;  // last iter: dummy re-read

    __builtin_amdgcn_s_barrier();           // (a) all reads of buf[p^1] retired
    gload_lds16(sAg[0] + ktn, SA + 0 * 4096 + w * 512);
    gload_lds16(sAg[1] + ktn, SA + 1 * 4096 + w * 512);
    asm volatile("s_waitcnt vmcnt(2)" ::: "memory");  // drain buf[p]'s 8; keep 2 in flight
    __builtin_amdgcn_s_barrier();           // (b) buf[p] staged for all waves
    __builtin_amdgcn_sched_barrier(0);

    const char* Ac = (const char*)LA;
    const char* Bc = (const char*)LB;
    s16x8 bf[4][2];
#pragma unroll
    for (int nf = 0; nf < 4; nf++)
#pragma unroll
      for (int ks = 0; ks < 2; ks++) {
        int row = wn * 64 + nf * 16 + r;
        bf[nf][ks] = *(const s16x8*)(Bc + ((row * 128 + ks * 64 + g * 16) ^ swz));
      }
#pragma unroll
    for (int ph = 0; ph < 4; ph++) {
      if (ph == 1) {
        gload_lds16(sAg[2] + ktn, SA + 2 * 4096 + w * 512);
        gload_lds16(sAg[3] + ktn, SA + 3 * 4096 + w * 512);
      } else if (ph == 2) {
        gload_lds16(sBg[0] + ktn, SB + 0 * 4096 + w * 512);
        gload_lds16(sBg[1] + ktn, SB + 1 * 4096 + w * 512);
      } else if (ph == 3) {
        gload_lds16(sBg[2] + ktn, SB + 2 * 4096 + w * 512);
        gload_lds16(sBg[3] + ktn, SB + 3 * 4096 + w * 512);
      }
      s16x8 af[2][2];
#pragma unroll
      for (int mi = 0; mi < 2; mi++)
#pragma unroll
        for (int ks = 0; ks < 2; ks++) {
          int row = wm * 128 + (ph * 2 + mi) * 16 + r;
          af[mi][ks] = *(const s16x8*)(Ac + ((row * 128 + ks * 64 + g * 16) ^ swz));
        }
      __builtin_amdgcn_s_setprio(1);
#pragma unroll
      for (int mi = 0; mi < 2; mi++)
#pragma unroll
        for (int nf = 0; nf < 4; nf++) {
          acc[ph * 2 + mi][nf] = __builtin_amdgcn_mfma_f32_16x16x32_bf16(
              af[mi][0], bf[nf][0], acc[ph * 2 + mi][nf], 0, 0, 0);
          acc[ph * 2 + mi][nf] = __builtin_amdgcn_mfma_f32_16x16x32_bf16(
              af[mi][1], bf[nf][1], acc[ph * 2 + mi][nf], 0, 0, 0);
        }
      __builtin_amdgcn_s_setprio(0);
    }
  }
  asm volatile("s_waitcnt vmcnt(0)" ::: "memory");  // drain dummy stage before endpgm

#pragma unroll
  for (int mf = 0; mf < 8; mf++)
#pragma unroll
    for (int nf = 0; nf < 4; nf++)
#pragma unroll
      for (int jj = 0; jj < 4; jj++) {
        size_t idx = (size_t)(bm + wm * 128 + mf * 16 + g * 4 + jj) * N +
                     (bn + wn * 64 + nf * 16 + r);
        if constexpr (OUT_BF16) ((u16*)Cv)[idx] = f2bf(acc[mf][nf][jj]);
        else                    ((float*)Cv)[idx] = acc[mf][nf][jj];
      }
}

// ---------- causal GQA flash attention, 4-wave blocks (QBLK=64), LDS-staged K/V ----------
// Q [b][28][S][128] bf16 (pre-scaled), K [b][4][S][128] bf16, Vt [b][4][128][S] bf16
// AO (B*S x 3584) bf16.  KVBLK=32.
// Work-uniform pairing over 32 q-tiles: block pp handles {pp, 31-pp} (66 kv-tiles).
// Counted vmcnt(4) double-buffer; deferred softmax reductions:
//  - defer check on LOCAL max (equivalent under __all), max-reduce only when triggered
//  - per-lane partial row-sums, single cross-lane reduce at epilogue.
__global__ __launch_bounds__(256, 4) void attn_kernel(const u16* __restrict__ Q,
                                                      const u16* __restrict__ K,
                                                      const u16* __restrict__ Vt,
                                                      u16* __restrict__ AO) {
  constexpr int S = 2048, NH = 28, NKV = 4, D = 128;
  __shared__ u16 Kl[2][32 * 128];  // [row][256B], stored byte ^= (row&7)<<4
  __shared__ u16 Vl[2][32 * 128];  // [d][64B],   stored byte ^= ((d>>1)&7)<<4
  const int tid = threadIdx.x;
  const int lane = tid & 63, w = tid >> 6;   // 4 waves
  const int r = lane & 15, g = lane >> 4;
  const int pp = blockIdx.x, h = blockIdx.y, b = blockIdx.z;
  const int kh = h & 3;
  const u16* Kb = K + ((size_t)(b * NKV + kh) * S) * D;
  const u16* Vb = Vt + ((size_t)(b * NKV + kh) * D) * S;

  // staging: 256 thr x 16B = 4KB per issue; 8KB tile -> 2 issues each for K and V.
  const u16 *sK[2], *sV[2];
#pragma unroll
  for (int i = 0; i < 2; i++) {
    int o = i * 4096 + tid * 16;
    int krow = o >> 8;
    int kcol = ((o & 255) ^ ((krow & 7) << 4)) >> 1;
    sK[i] = Kb + (size_t)krow * D + kcol;
    int p = o ^ (((o >> 7) & 7) << 4);
    sV[i] = Vb + (size_t)(p >> 6) * S + ((p & 63) >> 1);
  }

#pragma unroll 1
  for (int seg = 0; seg < 2; ++seg) {
    const int qt = seg ? (31 - pp) : pp;
    const int q0 = qt * 64 + w * 16;
    const u16* Qb = Q + ((size_t)(b * NH + h) * S + q0) * D;

    s16x8 qf[4];
#pragma unroll
    for (int kb = 0; kb < 4; kb++)
      qf[kb] = *(const s16x8*)(Qb + (size_t)r * D + kb * 32 + g * 8);

    f32x4 o8[8];
#pragma unroll
    for (int c = 0; c < 8; c++) o8[c] = (f32x4){0.f, 0.f, 0.f, 0.f};
    float m = -1e30f, lsum = 0.f;
    const int qg = q0 + r;
    const int NT = 2 * qt + 2;

    // prologue: issue tile 0 loads (4 per thread)
#pragma unroll
    for (int i = 0; i < 2; i++) {
      gload_lds16(sK[i], (u16*)Kl[0] + i * 2048 + tid * 8);
      gload_lds16(sV[i], (u16*)Vl[0] + i * 2048 + tid * 8);
    }

    int cur = 0;
#pragma unroll 1
    for (int t = 0; t < NT; ++t) {
      const int j = t * 32;
      if (t + 1 < NT) {
        const size_t jn = (size_t)(j + 32);
#pragma unroll
        for (int i = 0; i < 2; i++) {
          gload_lds16(sK[i] + jn * D, (u16*)Kl[cur ^ 1] + i * 2048 + tid * 8);
          gload_lds16(sV[i] + jn,     (u16*)Vl[cur ^ 1] + i * 2048 + tid * 8);
        }
        asm volatile("s_waitcnt vmcnt(4)" ::: "memory");  // drain current tile's 4
      } else {
        asm volatile("s_waitcnt vmcnt(0)" ::: "memory");
      }
      __builtin_amdgcn_s_barrier();   // buf[cur] staged for all waves
      __builtin_amdgcn_sched_barrier(0);
      if (j <= q0 + 15) {  // wave-uniform active check
        // ---- QK^T (swapped): lane holds P[kv=16*hi+g*4+jj][q=r] ----
        f32x4 st0 = (f32x4){0.f, 0.f, 0.f, 0.f};
        f32x4 st1 = (f32x4){0.f, 0.f, 0.f, 0.f};
        const int swz = (r & 7) << 4;
        const char* Kc = (const char*)Kl[cur];
        __builtin_amdgcn_s_setprio(1);
#pragma unroll
        for (int kb = 0; kb < 4; kb++) {
          int cb = (kb * 64 + g * 16) ^ swz;
          s16x8 kf = *(const s16x8*)(Kc + r * 256 + cb);
          st0 = __builtin_amdgcn_mfma_f32_16x16x32_bf16(kf, qf[kb], st0, 0, 0, 0);
        }
#pragma unroll
        for (int kb = 0; kb < 4; kb++) {
          int cb = (kb * 64 + g * 16) ^ swz;
          s16x8 kf = *(const s16x8*)(Kc + (r + 16) * 256 + cb);
          st1 = __builtin_amdgcn_mfma_f32_16x16x32_bf16(kf, qf[kb], st1, 0, 0, 0);
        }
        __builtin_amdgcn_s_setprio(0);
        float s8v[8];
        if (j + 31 <= q0) {  // fully unmasked tile
#pragma unroll
          for (int jj = 0; jj < 4; jj++) { s8v[jj] = st0[jj]; s8v[jj + 4] = st1[jj]; }
        } else {
#pragma unroll
          for (int jj = 0; jj < 4; jj++) {
            int kv0 = j + g * 4 + jj;
            s8v[jj] = (kv0 > qg) ? -1e30f : st0[jj];
            s8v[jj + 4] = (kv0 + 16 > qg) ? -1e30f : st1[jj];
          }
        }
        // ---- online softmax, deferred reductions ----
        float pm = fmaxf(fmaxf(fmaxf(s8v[0], s8v[1]), fmaxf(s8v[2], s8v[3])),
                         fmaxf(fmaxf(s8v[4], s8v[5]), fmaxf(s8v[6], s8v[7])));
        const bool defer = __all(pm <= m + 8.f);  // local-max check (equivalent)
        float fr = 1.f;
        if (!defer) {
          pm = fmaxf(pm, __shfl_xor(pm, 16));
          pm = fmaxf(pm, __shfl_xor(pm, 32));
          float mnew = fmaxf(m, pm);
          fr = __expf(m - mnew);
          m = mnew;
        }
        float pv[8], psum = 0.f;
#pragma unroll
        for (int i2 = 0; i2 < 8; i2++) { pv[i2] = __expf(s8v[i2] - m); psum += pv[i2]; }
        lsum = lsum * fr + psum;   // per-lane partial; cross-lane reduce at epilogue
        // ---- P -> bf16 ----
        unsigned pk[4];
#pragma unroll
        for (int i2 = 0; i2 < 4; i2++) {
          __hip_bfloat162 hv = __float22bfloat162_rn(make_float2(pv[2 * i2], pv[2 * i2 + 1]));
          union { __hip_bfloat162 h; unsigned u; } cv; cv.h = hv; pk[i2] = cv.u;
        }
        // ---- redistribute to A-fragment layout ----
        int L0 = r + ((g & 1) << 5);
        unsigned a0 = (unsigned)__shfl((int)pk[0], L0);
        unsigned a1 = (unsigned)__shfl((int)pk[1], L0);
        unsigned a2 = (unsigned)__shfl((int)pk[2], L0);
        unsigned a3 = (unsigned)__shfl((int)pk[3], L0);
        unsigned b0 = (unsigned)__shfl((int)pk[0], L0 + 16);
        unsigned b1 = (unsigned)__shfl((int)pk[1], L0 + 16);
        unsigned b2 = (unsigned)__shfl((int)pk[2], L0 + 16);
        unsigned b3 = (unsigned)__shfl((int)pk[3], L0 + 16);
        union { unsigned u[4]; s16x8 v; } pu;
        pu.u[0] = (g < 2) ? a0 : a2;
        pu.u[1] = (g < 2) ? a1 : a3;
        pu.u[2] = (g < 2) ? b0 : b2;
        pu.u[3] = (g < 2) ? b1 : b3;
        s16x8 pa = pu.v;
        float fB[4];
        if (!defer) {
#pragma unroll
          for (int jj = 0; jj < 4; jj++) fB[jj] = __shfl(fr, g * 4 + jj);
        }
        // ---- PV ----
        const char* Vc = (const char*)Vl[cur];
        __builtin_amdgcn_s_setprio(1);
#pragma unroll
        for (int c = 0; c < 8; c++) {
          int pbyte = (c * 16 + r) * 64 + g * 16;
          int vaddr = pbyte ^ ((r >> 1) << 4);
          s16x8 vf = *(const s16x8*)(Vc + vaddr);
          f32x4 oc = o8[c];
          if (!defer) { oc.x *= fB[0]; oc.y *= fB[1]; oc.z *= fB[2]; oc.w *= fB[3]; }
          o8[c] = __builtin_amdgcn_mfma_f32_16x16x32_bf16(pa, vf, oc, 0, 0, 0);
        }
        __builtin_amdgcn_s_setprio(0);
      }
      __builtin_amdgcn_s_barrier();   // all reads of buf[cur] retired
      cur ^= 1;
    }

    // epilogue: single cross-lane lsum reduce, then write
    float lrow = lsum;
    lrow += __shfl_xor(lrow, 16);
    lrow += __shfl_xor(lrow, 32);
    float lB[4];
#pragma unroll
    for (int jj = 0; jj < 4; jj++) lB[jj] = __shfl(lrow, g * 4 + jj);
#pragma unroll
    for (int c = 0; c < 8; c++)
#pragma unroll
      for (int jj = 0; jj < 4; jj++) {
        float val = o8[c][jj] / lB[jj];
        AO[(size_t)(b * S + q0 + g * 4 + jj) * 3584 + h * 128 + c * 16 + r] = f2bf(val);
      }
  }
}

// ---------- workspace layout (bytes) ----------
static const size_t OFF_XBF = 0;            // 4096x3584 bf16
static const size_t OFF_WQT = 29360128;     // 3584x3584 bf16  } contiguous ->
static const size_t OFF_WKT = 55050240;     // 512x3584 bf16   } combined BT
static const size_t OFF_WVT = 58720256;     // 512x3584 bf16   } [4608][3584]
static const size_t OFF_WOT = 62390272;     // 3584x3584 bf16
static const size_t OFF_TAB = 88080384;     // 2048x64 float2
static const size_t OFF_QBF = 89128960;     // [2][28][2048][128] bf16
static const size_t OFF_KBF = 118489088;    // [2][4][2048][128] bf16
static const size_t OFF_VT  = 122683392;    // [2][4][128][2048] bf16
static const size_t OFF_QKV = 126877696;    // 4096x4608 bf16 (fused QKV proj out)
static const size_t OFF_AO  = 164626432;    // 4096x3584 bf16
// total: 193986560 bytes (ws_size >= 202375168 verified earlier)

extern "C" void kernel_launch(void* const* d_in, const int* in_sizes, int n_in,
                              void* d_out, int out_size, void* d_ws, size_t ws_size,
                              hipStream_t stream) {
  const float* X  = (const float*)d_in[0];
  const float* Wq = (const float*)d_in[1];
  const float* Wk = (const float*)d_in[2];
  const float* Wv = (const float*)d_in[3];
  const float* Wo = (const float*)d_in[4];
  float* out = (float*)d_out;
  char* ws = (char*)d_ws;

  u16* Xbf = (u16*)(ws + OFF_XBF);
  u16* WqT = (u16*)(ws + OFF_WQT);
  u16* WkT = (u16*)(ws + OFF_WKT);
  u16* WvT = (u16*)(ws + OFF_WVT);
  u16* WoT = (u16*)(ws + OFF_WOT);
  float2* tab = (float2*)(ws + OFF_TAB);
  u16* Qbf = (u16*)(ws + OFF_QBF);
  u16* Kbf = (u16*)(ws + OFF_KBF);
  u16* Vtb = (u16*)(ws + OFF_VT);
  u16* QKV = (u16*)(ws + OFF_QKV);
  u16* AO  = (u16*)(ws + OFF_AO);

  hipFuncSetAttribute(reinterpret_cast<const void*>(gemm256<1>),
                      hipFuncAttributeMaxDynamicSharedMemorySize, 131072);
  hipFuncSetAttribute(reinterpret_cast<const void*>(gemm256<0>),
                      hipFuncAttributeMaxDynamicSharedMemorySize, 131072);

  // conversions
  cvt_bf16<<<14336, 256, 0, stream>>>(X, Xbf, 3670016);
  transpose_cvt<<<dim3(112, 112), 256, 0, stream>>>(Wq, WqT, 3584, 3584);
  transpose_cvt<<<dim3(16, 112), 256, 0, stream>>>(Wk, WkT, 3584, 512);
  transpose_cvt<<<dim3(16, 112), 256, 0, stream>>>(Wv, WvT, 3584, 512);
  transpose_cvt<<<dim3(112, 112), 256, 0, stream>>>(Wo, WoT, 3584, 3584);
  rope_table<<<2048, 64, 0, stream>>>(tab);

  // fused Q+K+V projection: BT = [WqT;WkT;WvT] (4608 x 3584), bf16 out
  gemm256<1><<<dim3(18, 16), 512, 131072, stream>>>(Xbf, WqT, QKV, 4096, 4608, 3584);

  // rope + pack (softmax scale folded into Q)
  rope_pack<<<28672, 256, 0, stream>>>(QKV, tab, Qbf, 28, 4608, 0, 0.08838834764831845f);
  rope_pack<<<4096, 256, 0, stream>>>(QKV, tab, Kbf, 4, 4608, 3584, 1.0f);
  pack_vt<<<dim3(64, 4, 8), 256, 0, stream>>>(QKV, Vtb, 4608, 4096);

  // attention (16 work-uniform q-tile pairs x 28 heads x 2 batch = 896 blocks)
  attn_kernel<<<dim3(16, 28, 2), 256, 0, stream>>>(Qbf, Kbf, Vtb, AO);

  // output projection (f32 out)
  gemm256<0><<<dim3(14, 16), 512, 131072, stream>>>(AO, WoT, out, 4096, 3584, 3584);
}